// Round 11
// baseline (216.429 us; speedup 1.0000x reference)
//
#include <hip/hip_runtime.h>

// ---------------------------------------------------------------------------
// NonLocalBlockND — bf16 MFMA pipeline, round 11.
// Change vs round 10 (everything else identical):
//  * Depth-4 SINGLE-BARRIER counted-vmcnt core (was depth-3, 2 barriers/step).
//    Per K-step: { vwait<8>; barrier; comp(kt); stage(kt+3) }.
//    Race-free proof: all waves pass barrier(kt) only after finishing
//    comp(kt-1); stage target slot (kt+3)&3 == (kt-1)&3 is therefore dead.
//    Barrier count halves; prefetch distance 2 -> 3 steps.
//    LDS 64 KB (4 x 16 KB slots) -> 2 blocks/CU.
// ws layout unchanged (112,066,560 bytes).
// ---------------------------------------------------------------------------

typedef __attribute__((ext_vector_type(8))) short bf16x8;
typedef __attribute__((ext_vector_type(4))) float f32x4;
typedef unsigned short u16;
struct alignas(8) u16x4 { u16 x, y, z, w; };
struct alignas(16) u16x8 { u16 e[8]; };

constexpr int B_ = 4, C_ = 256, N_ = 2304, CI_ = 128;
constexpr long long NN_ = (long long)N_ * N_;

constexpr size_t B_WB = 0;
constexpr size_t B_WZ = 589824;
constexpr size_t B_PW = 786432;
constexpr size_t B_R1 = 2359296;
constexpr size_t B_R2 = 16515072;
constexpr size_t B_GP = 30670848;
constexpr size_t B_F  = 37748736;
constexpr size_t B_A  = 69599232;

__device__ __forceinline__ u16 f2bf(float f) {
  unsigned u = __float_as_uint(f);
  u += 0x7fff + ((u >> 16) & 1);
  return (u16)(u >> 16);
}
__device__ __forceinline__ u16 f2h(float f) {
  _Float16 h = (_Float16)f;
  return __builtin_bit_cast(u16, h);
}
__device__ __forceinline__ float h2f(u16 u) {
  return (float)__builtin_bit_cast(_Float16, u);
}

__device__ __forceinline__ void gload16(const void* g, void* l) {
  __builtin_amdgcn_global_load_lds((const __attribute__((address_space(1))) void*)g,
                                   (__attribute__((address_space(3))) void*)l,
                                   16, 0, 0);
}

template<int N> __device__ __forceinline__ void vwait() {
  asm volatile("s_waitcnt vmcnt(%0)" :: "i"(N) : "memory");
}
__device__ __forceinline__ void barrier_() {
  asm volatile("" ::: "memory");
  __builtin_amdgcn_s_barrier();
  asm volatile("" ::: "memory");
}

// m204 bijective XCD-chunk swizzle (grid % 8 == 0 for all users).
__device__ __forceinline__ int xcd_swz() {
  const int nwg = (int)gridDim.x, orig = (int)blockIdx.x;
  const int q = nwg >> 3, r = nwg & 7;
  const int xcd = orig & 7, pos = orig >> 3;
  return (xcd < r ? xcd * (q + 1) : r * (q + 1) + (xcd - r) * q) + pos;
}

// ====== uniform 256-thread core: 128x128 tile, BK=32, depth-4 1-barrier ======
// T2 swizzle: S(row) = ((row>>1)&3)<<4 permutes the four 16B slots of each
// 64B LDS row. Stage pre-swizzles the GLOBAL source col; reads XOR kb.
__device__ __forceinline__ void stage32(const char* Ag, int ldaB,
                                        const char* Bg, int ldbB,
                                        char* As, char* Bs, int t) {
  #pragma unroll
  for (int c = 0; c < 2; ++c) {
    const int idx = (c * 256 + t) * 16;
    const int row = idx >> 6;
    const int gc = (idx & 63) ^ (((row >> 1) & 3) << 4);
    gload16(Ag + (size_t)row * ldaB + gc, As + idx);
    gload16(Bg + (size_t)row * ldbB + gc, Bs + idx);
  }
}

// One BK=32 K-step; kb arrives pre-XORed with S(l&15).
__device__ __forceinline__ void comp32(const char* As, const char* Bs,
                                       f32x4 (&acc)[4][4],
                                       int arow, int brow, int kb) {
  bf16x8 af[4], bfr[4];
  #pragma unroll
  for (int i = 0; i < 4; ++i) {
    af[i]  = *(const bf16x8*)(As + (arow + i * 16) * 64 + kb);
    bfr[i] = *(const bf16x8*)(Bs + (brow + i * 16) * 64 + kb);
  }
  __builtin_amdgcn_s_setprio(1);
  #pragma unroll
  for (int mf = 0; mf < 4; ++mf)
    #pragma unroll
    for (int nf = 0; nf < 4; ++nf)
      acc[mf][nf] = __builtin_amdgcn_mfma_f32_16x16x32_bf16(
          af[mf], bfr[nf], acc[mf][nf], 0, 0, 0);
  __builtin_amdgcn_s_setprio(0);
}

// Depth-4 ring, ONE barrier per K-step:
//   prologue: stage slots 0,1,2
//   loop kt:  vwait<8>; barrier; comp(slot kt&3); stage(kt+3 -> slot (kt+3)&3)
//   tail:     vwait<8/4/0>; barrier; comp for the last three staged slots.
// Requires kIters >= 3 (all users >= 4).
__device__ __forceinline__ void gemm256c(const char* Ab, int ldaB,
                                         const char* Bb, int ldbB,
                                         int kIters, f32x4 (&acc)[4][4],
                                         char* lds) {
  const int t = (int)threadIdx.x, l = t & 63, w = t >> 6;
  const int arow = (w >> 1) * 64 + (l & 15);
  const int brow = (w & 1) * 64 + (l & 15);
  const int kb = ((l >> 4) * 16) ^ ((((l & 15) >> 1) & 3) << 4);
  stage32(Ab,       ldaB, Bb,       ldbB, lds,         lds + 8192,  t);
  stage32(Ab + 64,  ldaB, Bb + 64,  ldbB, lds + 16384, lds + 24576, t);
  stage32(Ab + 128, ldaB, Bb + 128, ldbB, lds + 32768, lds + 40960, t);
  for (int kt = 0; kt + 4 <= kIters; ++kt) {
    char* slot = lds + ((kt & 3) * 16384);
    char* nslot = lds + (((kt + 3) & 3) * 16384);
    vwait<8>();
    barrier_();
    comp32(slot, slot + 8192, acc, arow, brow, kb);
    stage32(Ab + (size_t)(kt + 3) * 64, ldaB,
            Bb + (size_t)(kt + 3) * 64, ldbB, nslot, nslot + 8192, t);
  }
  {
    char* slot = lds + (((kIters - 3) & 3) * 16384);
    vwait<8>();
    barrier_();
    comp32(slot, slot + 8192, acc, arow, brow, kb);
  }
  {
    char* slot = lds + (((kIters - 2) & 3) * 16384);
    vwait<4>();
    barrier_();
    comp32(slot, slot + 8192, acc, arow, brow, kb);
  }
  {
    char* slot = lds + (((kIters - 1) & 3) * 16384);
    vwait<0>();
    barrier_();
    comp32(slot, slot + 8192, acc, arow, brow, kb);
  }
}

#define EPI_SETUP \
  const int el = (int)threadIdx.x & 63, ew = (int)threadIdx.x >> 6; \
  const int rb = (ew >> 1) * 64 + ((el >> 4) << 2); \
  const int cb = (ew & 1) * 64 + (el & 15);

// ---------------- weight convert ----------------
struct CvtW { const float* s[13]; };
__global__ __launch_bounds__(256) void k_cvtw(CvtW cw, u16* dst) {
  const int seg = blockIdx.y;
  const int i = (blockIdx.x * 256 + threadIdx.x) * 4;
  const int sz = (seg == 12) ? 786432 : 32768;
  if (i >= sz) return;
  size_t off = (seg < 9) ? (size_t)seg * 32768
             : (seg < 12) ? 294912 + (size_t)(seg - 9) * 32768
                          : 393216;
  f32x4 v = *(const f32x4*)(cw.s[seg] + i);
  u16x4 o; o.x = f2bf(v[0]); o.y = f2bf(v[1]); o.z = f2bf(v[2]); o.w = f2bf(v[3]);
  *(u16x4*)(dst + off + i) = o;
}

// ---------------- x transpose-convert: (b,c,n) -> xbT[vb][q][c] ----------------
__global__ __launch_bounds__(256) void k_cvtx(const float* x0, const float* x1,
                                              const float* x2, u16* XT) {
  __shared__ float tile[64][65];
  const int t = threadIdx.x;
  const int q0 = blockIdx.x * 64, c0 = blockIdx.y * 64;
  const int vb = blockIdx.z, v = vb >> 2, b = vb & 3;
  const float* src = (v == 0 ? x0 : v == 1 ? x1 : x2) + ((size_t)b * C_ + c0) * N_ + q0;
  #pragma unroll
  for (int i = 0; i < 4; ++i) {
    int idx = t + i * 256;
    int r = idx >> 4, q4 = (idx & 15) * 4;
    f32x4 val = *(const f32x4*)(src + (size_t)r * N_ + q4);
    tile[r][q4 + 0] = val[0]; tile[r][q4 + 1] = val[1];
    tile[r][q4 + 2] = val[2]; tile[r][q4 + 3] = val[3];
  }
  __syncthreads();
  u16* dst = XT + ((size_t)vb * N_ + q0) * 256 + c0;
  const int q = t >> 2, cp = (t & 3) * 16;
  u16 tmp[16];
  #pragma unroll
  for (int jj = 0; jj < 16; ++jj) tmp[jj] = f2bf(tile[cp + jj][q]);
  #pragma unroll
  for (int s4 = 0; s4 < 4; ++s4) {
    u16x4 o; o.x = tmp[s4 * 4]; o.y = tmp[s4 * 4 + 1];
    o.z = tmp[s4 * 4 + 2]; o.w = tmp[s4 * 4 + 3];
    *(u16x4*)(dst + (size_t)q * 256 + cp + s4 * 4) = o;
  }
}

// ---------------- proj (256t, grid (18,1,36), kIters=8) ----------------
struct ProjA { const float* bias[9]; };
__global__ __launch_bounds__(256) void k_proj(const u16* WB, const u16* XT,
                                              u16* TH, u16* PH, u16* GP, ProjA pa) {
  __shared__ char lds[65536];
  const int col0 = blockIdx.x * 128;                 // q
  const int p = blockIdx.z >> 2, b = blockIdx.z & 3;
  const int v = p / 3, pt = p % 3;
  const char* Ab = (const char*)(WB + (size_t)p * 32768);
  const char* Bb = (const char*)(XT + ((size_t)(v * 4 + b) * N_ + col0) * 256);
  f32x4 acc[4][4] = {};
  gemm256c(Ab, 512, Bb, 512, 8, acc, lds);
  EPI_SETUP;
  const float* bias = pa.bias[p];
  if (pt == 0) {                                     // g -> (ci, m) natural
    u16* dst = GP + (size_t)(v * 4 + b) * CI_ * N_;
    #pragma unroll
    for (int mf = 0; mf < 4; ++mf) {
      const int row = rb + mf * 16;
      f32x4 bv = *(const f32x4*)(bias + row);
      #pragma unroll
      for (int nf = 0; nf < 4; ++nf) {
        const int col = col0 + cb + nf * 16;
        #pragma unroll
        for (int r = 0; r < 4; ++r)
          dst[(size_t)(row + r) * N_ + col] = f2bf(acc[mf][nf][r] + bv[r]);
      }
    }
  } else {                                           // theta/phi -> (q, ci)
    u16* dst = (pt == 1 ? TH : PH) + (size_t)(v * 4 + b) * N_ * CI_;
    #pragma unroll
    for (int mf = 0; mf < 4; ++mf) {
      const int row = rb + mf * 16;                  // ci
      f32x4 bv = *(const f32x4*)(bias + row);
      #pragma unroll
      for (int nf = 0; nf < 4; ++nf) {
        const int col = col0 + cb + nf * 16;         // q
        u16x4 o;
        o.x = f2bf(acc[mf][nf][0] + bv[0]); o.y = f2bf(acc[mf][nf][1] + bv[1]);
        o.z = f2bf(acc[mf][nf][2] + bv[2]); o.w = f2bf(acc[mf][nf][3] + bv[3]);
        *(u16x4*)(dst + (size_t)col * CI_ + row) = o;
      }
    }
  }
}

// ---------------- score (256t, grid (18,18,3), kIters=4) ----------------
__global__ __launch_bounds__(256) void k_score(const u16* TH, const u16* PH,
                                               u16* F, int b) {
  __shared__ char lds[65536];
  const int col0 = blockIdx.x * 128;   // k
  const int row0 = blockIdx.y * 128;   // q
  const int br = blockIdx.z;
  const char* Ab = (const char*)(TH + ((size_t)(br * 4 + b) * N_ + row0) * CI_);
  const char* Bb = (const char*)(PH + ((size_t)(br * 4 + b) * N_ + col0) * CI_);
  f32x4 acc[4][4] = {};
  gemm256c(Ab, 256, Bb, 256, 4, acc, lds);
  EPI_SETUP;
  const int t = (int)threadIdx.x;
  __syncthreads();                      // K-loop LDS reads done; reuse as [128][136]
  u16* tl = (u16*)lds;
  #pragma unroll
  for (int mf = 0; mf < 4; ++mf)
    #pragma unroll
    for (int nf = 0; nf < 4; ++nf)
      #pragma unroll
      for (int r = 0; r < 4; ++r)
        tl[(rb + mf * 16 + r) * 136 + cb + nf * 16] = f2h(acc[mf][nf][r]);
  __syncthreads();
  u16* dst = F + (size_t)br * NN_;
  const int k8 = (t & 15) * 8;
  #pragma unroll
  for (int rr = 0; rr < 8; ++rr) {
    const int q = (t >> 4) + rr * 16;
    *(u16x8*)(dst + (size_t)(row0 + q) * N_ + col0 + k8) =
        *(const u16x8*)(tl + q * 136 + k8);
  }
}

// ---------------- softsum: A-row = sum of 3 softmaxes (no max pass) ----------
__device__ __forceinline__ float blk_sum(float v, float* red) {
  #pragma unroll
  for (int o = 32; o; o >>= 1) v += __shfl_xor(v, o);
  int w = threadIdx.x >> 6;
  __syncthreads();
  if ((threadIdx.x & 63) == 0) red[w] = v;
  __syncthreads();
  return red[0] + red[1] + red[2] + red[3];
}

__global__ __launch_bounds__(256) void k_softsum(const u16* F, u16* Abf, int b) {
  __shared__ float red[4];
  const int q = blockIdx.x, t = threadIdx.x;
  const bool ext = (t < 32);
  float outv[16] = {};
  #pragma unroll
  for (int i = 0; i < 3; ++i) {
    const u16* base = F + (size_t)i * NN_ + (size_t)q * N_;
    float e[16];
    u16x8 a = *(const u16x8*)(base + t * 8);
    #pragma unroll
    for (int jj = 0; jj < 8; ++jj) e[jj] = __expf(h2f(a.e[jj]));
    if (ext) {
      u16x8 c = *(const u16x8*)(base + 2048 + t * 8);
      #pragma unroll
      for (int jj = 0; jj < 8; ++jj) e[8 + jj] = __expf(h2f(c.e[jj]));
    } else {
      #pragma unroll
      for (int jj = 0; jj < 8; ++jj) e[8 + jj] = 0.f;
    }
    float ssum = 0.f;
    #pragma unroll
    for (int s = 0; s < 16; ++s) ssum += e[s];
    ssum = blk_sum(ssum, red);
    const float inv = 1.f / ssum;
    #pragma unroll
    for (int s = 0; s < 16; ++s) outv[s] += e[s] * inv;
  }
  u16* dst = Abf + ((size_t)b * N_ + q) * N_;
  u16x8 o;
  #pragma unroll
  for (int jj = 0; jj < 8; ++jj) o.e[jj] = f2bf(outv[jj]);
  *(u16x8*)(dst + t * 8) = o;
  if (ext) {
    #pragma unroll
    for (int jj = 0; jj < 8; ++jj) o.e[jj] = f2bf(outv[8 + jj]);
    *(u16x8*)(dst + 2048 + t * 8) = o;
  }
}

// ---------------- pv (256t, K-split x2, grid 432, kIters=36) ----------------
__global__ __launch_bounds__(256) void k_pv(const u16* Abf, const u16* GP,
                                            float* P) {
  __shared__ char lds[65536];
  const int lid = xcd_swz();
  const int j = lid % 3;
  const int row0 = ((lid / 3) % 18) * 128; // q
  const int z = lid / 54;
  const int b = z >> 1, s = z & 1;
  const char* Ab = (const char*)(Abf + ((size_t)b * N_ + row0) * N_ + s * 1152);
  const char* Bb = (const char*)(GP + (size_t)(j * 4 + b) * CI_ * N_ + s * 1152);
  f32x4 acc[4][4] = {};
  gemm256c(Ab, 4608, Bb, 4608, 36, acc, lds);
  EPI_SETUP;
  const int t = (int)threadIdx.x;
  float* dst = P + ((size_t)(s * 4 + b) * N_) * 384;
  float* tl = (float*)lds;
  const int jc4 = (t & 15) * 4;
  #pragma unroll
  for (int p = 0; p < 2; ++p) {
    __syncthreads();
    if ((ew & 1) == p) {
      #pragma unroll
      for (int mf = 0; mf < 4; ++mf)
        #pragma unroll
        for (int nf = 0; nf < 4; ++nf)
          #pragma unroll
          for (int r = 0; r < 4; ++r)
            tl[(rb + mf * 16 + r) * 68 + (el & 15) + nf * 16] = acc[mf][nf][r];
    }
    __syncthreads();
    #pragma unroll
    for (int rr = 0; rr < 8; ++rr) {
      const int q = (t >> 4) + rr * 16;
      *(f32x4*)(dst + (size_t)(row0 + q) * 384 + j * 128 + p * 64 + jc4) =
          *(const f32x4*)(tl + q * 68 + jc4);
    }
  }
}

__global__ __launch_bounds__(256) void k_pvred(const float* P, u16* Y) {
  const size_t i4 = (size_t)blockIdx.x * 256 + threadIdx.x;
  constexpr size_t HALF = (size_t)4 * N_ * 384;
  f32x4 a = *(const f32x4*)(P + i4 * 4);
  f32x4 c = *(const f32x4*)(P + HALF + i4 * 4);
  u16x4 o; o.x = f2bf(a[0] + c[0]); o.y = f2bf(a[1] + c[1]);
  o.z = f2bf(a[2] + c[2]); o.w = f2bf(a[3] + c[3]);
  *(u16x4*)(Y + i4 * 4) = o;
}

// ---------------- zcat (256t, grid (18,2,12), kIters=4) ----------------
struct ZA { const float* x[3]; const float* wzb[3]; const float* dww; const float* dwb; };
__global__ __launch_bounds__(256) void k_zcat(const u16* WZ, const u16* Y,
                                              u16* DW, ZA za) {
  __shared__ char lds[65536];
  const int col0 = blockIdx.x * 128;                 // q
  const int row0 = blockIdx.y * 128;                 // c within 256
  const int j = blockIdx.z >> 2, b = blockIdx.z & 3;
  const char* Ab = (const char*)(WZ + (size_t)j * 32768 + (size_t)row0 * CI_);
  const char* Bb = (const char*)(Y + ((size_t)b * N_ + col0) * 384 + j * CI_);
  f32x4 acc[4][4] = {};
  gemm256c(Ab, 256, Bb, 768, 4, acc, lds);
  EPI_SETUP;
  const float* xj = za.x[j];
  #pragma unroll
  for (int mf = 0; mf < 4; ++mf) {
    const int cl = row0 + rb + mf * 16;              // 0..255
    const int cg = j * 256 + cl;
    f32x4 wb = *(const f32x4*)(za.wzb[j] + cl);
    f32x4 sc = *(const f32x4*)(za.dww + cg);
    f32x4 sb = *(const f32x4*)(za.dwb + cg);
    #pragma unroll
    for (int nf = 0; nf < 4; ++nf) {
      const int qg = col0 + cb + nf * 16;
      u16x4 o;
      o.x = f2bf((acc[mf][nf][0] + wb[0] + xj[((size_t)b * C_ + cl + 0) * N_ + qg]) * sc[0] + sb[0]);
      o.y = f2bf((acc[mf][nf][1] + wb[1] + xj[((size_t)b * C_ + cl + 1) * N_ + qg]) * sc[1] + sb[1]);
      o.z = f2bf((acc[mf][nf][2] + wb[2] + xj[((size_t)b * C_ + cl + 2) * N_ + qg]) * sc[2] + sb[2]);
      o.w = f2bf((acc[mf][nf][3] + wb[3] + xj[((size_t)b * C_ + cl + 3) * N_ + qg]) * sc[3] + sb[3]);
      *(u16x4*)(DW + ((size_t)b * N_ + qg) * 768 + cg) = o;
    }
  }
}

// ---------------- final (256t, grid 576 swizzled, kIters=24) -----------------
__global__ __launch_bounds__(256) void k_final(const u16* PWb, const u16* DW,
                                               const float* pwb, const float* xin,
                                               const float* pp, float* out) {
  __shared__ char lds[65536];
  const int lid = xcd_swz();
  const int row0 = (lid % 18) * 128;        // q strip
  const int col0 = ((lid / 18) % 8) * 128;  // o strip
  const int b = lid / 144;
  const char* Ab = (const char*)(DW + ((size_t)b * N_ + row0) * 768);
  const char* Bb = (const char*)(PWb + (size_t)col0 * 768);
  EPI_SETUP;
  const int t = (int)threadIdx.x;
  const float pscale = pp[0];
  const int q4 = (t & 31) * 4;
  const int ob = (t >> 5) * 8;
  f32x4 xv[2][8];
  #pragma unroll
  for (int p = 0; p < 2; ++p)
    #pragma unroll
    for (int rr = 0; rr < 8; ++rr)
      xv[p][rr] = *(const f32x4*)(
          xin + ((size_t)b * 1024 + col0 + p * 64 + ob + rr) * N_ + row0 + q4);
  f32x4 acc[4][4] = {};
  gemm256c(Ab, 1536, Bb, 1536, 24, acc, lds);
  float* tl = (float*)lds;
  #pragma unroll
  for (int p = 0; p < 2; ++p) {
    __syncthreads();
    if ((ew & 1) == p) {                   // this wave-column owns o-half p
      #pragma unroll
      for (int mf = 0; mf < 4; ++mf)
        #pragma unroll
        for (int nf = 0; nf < 4; ++nf)
          #pragma unroll
          for (int r = 0; r < 4; ++r)
            tl[((el & 15) + nf * 16) * 132 + rb + mf * 16 + r] = acc[mf][nf][r];
    }
    __syncthreads();
    #pragma unroll
    for (int rr = 0; rr < 8; ++rr) {
      const int og = col0 + p * 64 + ob + rr;
      const float bb = pwb[og];
      f32x4 a4 = *(const f32x4*)(tl + (ob + rr) * 132 + q4);
      f32x4 o4;
      #pragma unroll
      for (int r = 0; r < 4; ++r)
        o4[r] = xv[p][rr][r] + pscale * (a4[r] + bb);
      *(f32x4*)(out + ((size_t)b * 1024 + og) * N_ + row0 + q4) = o4;
    }
  }
}

// ---------------------------------------------------------------------------
extern "C" void kernel_launch(void* const* d_in, const int* in_sizes, int n_in,
                              void* d_out, int out_size, void* d_ws, size_t ws_size,
                              hipStream_t stream) {
  const float* x0  = (const float*)d_in[0];
  const float* x1  = (const float*)d_in[1];
  const float* x2  = (const float*)d_in[2];
  const float* xin = (const float*)d_in[3];
  const float* g_w = (const float*)d_in[4];
  const float* g_b = (const float*)d_in[5];
  const float* thw[3] = {(const float*)d_in[6],  (const float*)d_in[10], (const float*)d_in[14]};
  const float* thb[3] = {(const float*)d_in[7],  (const float*)d_in[11], (const float*)d_in[15]};
  const float* phw[3] = {(const float*)d_in[8],  (const float*)d_in[12], (const float*)d_in[16]};
  const float* phb[3] = {(const float*)d_in[9],  (const float*)d_in[13], (const float*)d_in[17]};
  const float* Wm[3]  = {(const float*)d_in[18], (const float*)d_in[20], (const float*)d_in[22]};
  const float* Wmb[3] = {(const float*)d_in[19], (const float*)d_in[21], (const float*)d_in[23]};
  const float* dww = (const float*)d_in[24];
  const float* dwb = (const float*)d_in[25];
  const float* pww = (const float*)d_in[26];
  const float* pwb = (const float*)d_in[27];
  const float* pp  = (const float*)d_in[28];

  char* wsb = (char*)d_ws;
  u16*   WB  = (u16*)(wsb + B_WB);
  u16*   WZ  = (u16*)(wsb + B_WZ);
  u16*   PW  = (u16*)(wsb + B_PW);
  u16*   XT  = (u16*)(wsb + B_R1);
  u16*   Y   = (u16*)(wsb + B_R1);   // overlays XT (dead after k_proj)
  u16*   TH  = (u16*)(wsb + B_R2);
  u16*   PH  = TH + (size_t)3 * B_ * N_ * CI_;
  u16*   DW  = (u16*)(wsb + B_R2);   // overlays TH/PH (dead after last k_score)
  u16*   GP  = (u16*)(wsb + B_GP);
  u16*   Fh  = (u16*)(wsb + B_F);    // fp16 scores, per batch
  float* Pp  = (float*)(wsb + B_F);  // pv partials overlay (Fh dead after softsum)
  u16*   Abf = (u16*)(wsb + B_A);

  CvtW cw;
  cw.s[0] = g_w; cw.s[1] = thw[0]; cw.s[2] = phw[0];
  cw.s[3] = g_w; cw.s[4] = thw[1]; cw.s[5] = phw[1];
  cw.s[6] = g_w; cw.s[7] = thw[2]; cw.s[8] = phw[2];
  cw.s[9] = Wm[0]; cw.s[10] = Wm[1]; cw.s[11] = Wm[2];
  cw.s[12] = pww;

  ProjA pa;
  pa.bias[0] = g_b; pa.bias[1] = thb[0]; pa.bias[2] = phb[0];
  pa.bias[3] = g_b; pa.bias[4] = thb[1]; pa.bias[5] = phb[1];
  pa.bias[6] = g_b; pa.bias[7] = thb[2]; pa.bias[8] = phb[2];

  ZA za;
  za.x[0] = x0; za.x[1] = x1; za.x[2] = x2;
  za.wzb[0] = Wmb[0]; za.wzb[1] = Wmb[1]; za.wzb[2] = Wmb[2];
  za.dww = dww; za.dwb = dwb;

  k_cvtw<<<dim3(768, 13), 256, 0, stream>>>(cw, WB);
  k_cvtx<<<dim3(36, 4, 12), 256, 0, stream>>>(x0, x1, x2, XT);
  k_proj<<<dim3(18, 1, 36), 256, 0, stream>>>(WB, XT, TH, PH, GP, pa);
  for (int b = 0; b < B_; ++b) {
    k_score  <<<dim3(18, 18, 3), 256, 0, stream>>>(TH, PH, Fh, b);
    k_softsum<<<dim3(N_),        256, 0, stream>>>(Fh, Abf, b);
  }
  k_pv   <<<dim3(432),  256, 0, stream>>>(Abf, GP, Pp);
  k_pvred<<<dim3(3456), 256, 0, stream>>>(Pp, Y);
  k_zcat <<<dim3(18, 2, 12), 256, 0, stream>>>(WZ, Y, DW, za);
  k_final<<<dim3(576),  256, 0, stream>>>(PW, DW, pwb, xin, pp, (float*)d_out);
}

// Round 12
// 215.539 us; speedup vs baseline: 1.0041x; 1.0041x over previous
//
#include <hip/hip_runtime.h>

// ---------------------------------------------------------------------------
// NonLocalBlockND — bf16 MFMA pipeline, round 12.
// Changes vs round 10 (the 210-us baseline; round 11's single-barrier core
// for the small kernels is reverted):
//  * k_final: 512-thread 256x128 tile (8 waves, per-wave 64x64), BK=32,
//    depth-4 SINGLE-barrier counted-vmcnt ring (4 x 24 KB = 96 KB LDS).
//    Per K-step: 128 MFMA per block-barrier (was 64) and 24 KB staged
//    (two 128^2 blocks staged 32 KB) -> +33% compute per staged byte,
//    half the barrier crossings per MFMA. vwait<6/6/3/0> (3 VMEM/th/step).
//    xin f32x4 prefetch kept (issued oldest; first vwait<6> drains
//    xin + own stage0 exactly). LDS-transpose epilogue -> 1KB-coalesced
//    f32x4 out stores. Grid 9x8x4 = 288 (%8==0), XCD-chunk swizzled.
//  * proj/score/zcat/pv: identical to round 10 (depth-3, 2-barrier, 48 KB).
// ws layout unchanged (112,066,560 bytes).
// ---------------------------------------------------------------------------

typedef __attribute__((ext_vector_type(8))) short bf16x8;
typedef __attribute__((ext_vector_type(4))) float f32x4;
typedef unsigned short u16;
struct alignas(8) u16x4 { u16 x, y, z, w; };
struct alignas(16) u16x8 { u16 e[8]; };

constexpr int B_ = 4, C_ = 256, N_ = 2304, CI_ = 128;
constexpr long long NN_ = (long long)N_ * N_;

constexpr size_t B_WB = 0;
constexpr size_t B_WZ = 589824;
constexpr size_t B_PW = 786432;
constexpr size_t B_R1 = 2359296;
constexpr size_t B_R2 = 16515072;
constexpr size_t B_GP = 30670848;
constexpr size_t B_F  = 37748736;
constexpr size_t B_A  = 69599232;

__device__ __forceinline__ u16 f2bf(float f) {
  unsigned u = __float_as_uint(f);
  u += 0x7fff + ((u >> 16) & 1);
  return (u16)(u >> 16);
}
__device__ __forceinline__ u16 f2h(float f) {
  _Float16 h = (_Float16)f;
  return __builtin_bit_cast(u16, h);
}
__device__ __forceinline__ float h2f(u16 u) {
  return (float)__builtin_bit_cast(_Float16, u);
}

__device__ __forceinline__ void gload16(const void* g, void* l) {
  __builtin_amdgcn_global_load_lds((const __attribute__((address_space(1))) void*)g,
                                   (__attribute__((address_space(3))) void*)l,
                                   16, 0, 0);
}

template<int N> __device__ __forceinline__ void vwait() {
  asm volatile("s_waitcnt vmcnt(%0)" :: "i"(N) : "memory");
}
__device__ __forceinline__ void barrier_() {
  asm volatile("" ::: "memory");
  __builtin_amdgcn_s_barrier();
  asm volatile("" ::: "memory");
}

// m204 bijective XCD-chunk swizzle (grid % 8 == 0 for all users).
__device__ __forceinline__ int xcd_swz() {
  const int nwg = (int)gridDim.x, orig = (int)blockIdx.x;
  const int q = nwg >> 3, r = nwg & 7;
  const int xcd = orig & 7, pos = orig >> 3;
  return (xcd < r ? xcd * (q + 1) : r * (q + 1) + (xcd - r) * q) + pos;
}

// ========== 256-thread core: 128x128 tile, BK=32, depth-3 ring (R10) ========
// T2 swizzle: S(row) = ((row>>1)&3)<<4 permutes the four 16B slots of each
// 64B LDS row. Stage pre-swizzles the GLOBAL source col; reads XOR kb.
__device__ __forceinline__ void stage32(const char* Ag, int ldaB,
                                        const char* Bg, int ldbB,
                                        char* As, char* Bs, int t) {
  #pragma unroll
  for (int c = 0; c < 2; ++c) {
    const int idx = (c * 256 + t) * 16;
    const int row = idx >> 6;
    const int gc = (idx & 63) ^ (((row >> 1) & 3) << 4);
    gload16(Ag + (size_t)row * ldaB + gc, As + idx);
    gload16(Bg + (size_t)row * ldbB + gc, Bs + idx);
  }
}

// One BK=32 K-step; kb arrives pre-XORed with S(l&15). Stride 64 B rows.
__device__ __forceinline__ void comp32(const char* As, const char* Bs,
                                       f32x4 (&acc)[4][4],
                                       int arow, int brow, int kb) {
  bf16x8 af[4], bfr[4];
  #pragma unroll
  for (int i = 0; i < 4; ++i) {
    af[i]  = *(const bf16x8*)(As + (arow + i * 16) * 64 + kb);
    bfr[i] = *(const bf16x8*)(Bs + (brow + i * 16) * 64 + kb);
  }
  __builtin_amdgcn_s_setprio(1);
  #pragma unroll
  for (int mf = 0; mf < 4; ++mf)
    #pragma unroll
    for (int nf = 0; nf < 4; ++nf)
      acc[mf][nf] = __builtin_amdgcn_mfma_f32_16x16x32_bf16(
          af[mf], bfr[nf], acc[mf][nf], 0, 0, 0);
  __builtin_amdgcn_s_setprio(0);
}

// Depth-3 counted vmcnt (R10); requires kIters >= 3 (all users >= 4).
__device__ __forceinline__ void gemm256c(const char* Ab, int ldaB,
                                         const char* Bb, int ldbB,
                                         int kIters, f32x4 (&acc)[4][4],
                                         char* lds) {
  const int t = (int)threadIdx.x, l = t & 63, w = t >> 6;
  const int arow = (w >> 1) * 64 + (l & 15);
  const int brow = (w & 1) * 64 + (l & 15);
  const int kb = ((l >> 4) * 16) ^ ((((l & 15) >> 1) & 3) << 4);
  char* A0 = lds;          char* B0 = lds + 8192;
  char* A1 = lds + 16384;  char* B1 = lds + 24576;
  char* A2 = lds + 32768;  char* B2 = lds + 40960;
  stage32(Ab,      ldaB, Bb,      ldbB, A0, B0, t);
  stage32(Ab + 64, ldaB, Bb + 64, ldbB, A1, B1, t);
  for (int kt = 0; kt < kIters - 2; ++kt) {
    stage32(Ab + (size_t)(kt + 2) * 64, ldaB,
            Bb + (size_t)(kt + 2) * 64, ldbB, A2, B2, t);
    vwait<8>();
    barrier_();
    comp32(A0, B0, acc, arow, brow, kb);
    barrier_();
    char* ta = A0; A0 = A1; A1 = A2; A2 = ta;
    char* tb = B0; B0 = B1; B1 = B2; B2 = tb;
  }
  vwait<4>();
  barrier_();
  comp32(A0, B0, acc, arow, brow, kb);
  vwait<0>();
  barrier_();
  comp32(A1, B1, acc, arow, brow, kb);
}

#define EPI_SETUP \
  const int el = (int)threadIdx.x & 63, ew = (int)threadIdx.x >> 6; \
  const int rb = (ew >> 1) * 64 + ((el >> 4) << 2); \
  const int cb = (ew & 1) * 64 + (el & 15);

// ---------------- weight convert ----------------
struct CvtW { const float* s[13]; };
__global__ __launch_bounds__(256) void k_cvtw(CvtW cw, u16* dst) {
  const int seg = blockIdx.y;
  const int i = (blockIdx.x * 256 + threadIdx.x) * 4;
  const int sz = (seg == 12) ? 786432 : 32768;
  if (i >= sz) return;
  size_t off = (seg < 9) ? (size_t)seg * 32768
             : (seg < 12) ? 294912 + (size_t)(seg - 9) * 32768
                          : 393216;
  f32x4 v = *(const f32x4*)(cw.s[seg] + i);
  u16x4 o; o.x = f2bf(v[0]); o.y = f2bf(v[1]); o.z = f2bf(v[2]); o.w = f2bf(v[3]);
  *(u16x4*)(dst + off + i) = o;
}

// ---------------- x transpose-convert: (b,c,n) -> xbT[vb][q][c] ----------------
__global__ __launch_bounds__(256) void k_cvtx(const float* x0, const float* x1,
                                              const float* x2, u16* XT) {
  __shared__ float tile[64][65];
  const int t = threadIdx.x;
  const int q0 = blockIdx.x * 64, c0 = blockIdx.y * 64;
  const int vb = blockIdx.z, v = vb >> 2, b = vb & 3;
  const float* src = (v == 0 ? x0 : v == 1 ? x1 : x2) + ((size_t)b * C_ + c0) * N_ + q0;
  #pragma unroll
  for (int i = 0; i < 4; ++i) {
    int idx = t + i * 256;
    int r = idx >> 4, q4 = (idx & 15) * 4;
    f32x4 val = *(const f32x4*)(src + (size_t)r * N_ + q4);
    tile[r][q4 + 0] = val[0]; tile[r][q4 + 1] = val[1];
    tile[r][q4 + 2] = val[2]; tile[r][q4 + 3] = val[3];
  }
  __syncthreads();
  u16* dst = XT + ((size_t)vb * N_ + q0) * 256 + c0;
  const int q = t >> 2, cp = (t & 3) * 16;
  u16 tmp[16];
  #pragma unroll
  for (int jj = 0; jj < 16; ++jj) tmp[jj] = f2bf(tile[cp + jj][q]);
  #pragma unroll
  for (int s4 = 0; s4 < 4; ++s4) {
    u16x4 o; o.x = tmp[s4 * 4]; o.y = tmp[s4 * 4 + 1];
    o.z = tmp[s4 * 4 + 2]; o.w = tmp[s4 * 4 + 3];
    *(u16x4*)(dst + (size_t)q * 256 + cp + s4 * 4) = o;
  }
}

// ---------------- proj (256t, grid (18,1,36), kIters=8) ----------------
struct ProjA { const float* bias[9]; };
__global__ __launch_bounds__(256) void k_proj(const u16* WB, const u16* XT,
                                              u16* TH, u16* PH, u16* GP, ProjA pa) {
  __shared__ char lds[49152];
  const int col0 = blockIdx.x * 128;                 // q
  const int p = blockIdx.z >> 2, b = blockIdx.z & 3;
  const int v = p / 3, pt = p % 3;
  const char* Ab = (const char*)(WB + (size_t)p * 32768);
  const char* Bb = (const char*)(XT + ((size_t)(v * 4 + b) * N_ + col0) * 256);
  f32x4 acc[4][4] = {};
  gemm256c(Ab, 512, Bb, 512, 8, acc, lds);
  EPI_SETUP;
  const float* bias = pa.bias[p];
  if (pt == 0) {                                     // g -> (ci, m) natural
    u16* dst = GP + (size_t)(v * 4 + b) * CI_ * N_;
    #pragma unroll
    for (int mf = 0; mf < 4; ++mf) {
      const int row = rb + mf * 16;
      f32x4 bv = *(const f32x4*)(bias + row);
      #pragma unroll
      for (int nf = 0; nf < 4; ++nf) {
        const int col = col0 + cb + nf * 16;
        #pragma unroll
        for (int r = 0; r < 4; ++r)
          dst[(size_t)(row + r) * N_ + col] = f2bf(acc[mf][nf][r] + bv[r]);
      }
    }
  } else {                                           // theta/phi -> (q, ci)
    u16* dst = (pt == 1 ? TH : PH) + (size_t)(v * 4 + b) * N_ * CI_;
    #pragma unroll
    for (int mf = 0; mf < 4; ++mf) {
      const int row = rb + mf * 16;                  // ci
      f32x4 bv = *(const f32x4*)(bias + row);
      #pragma unroll
      for (int nf = 0; nf < 4; ++nf) {
        const int col = col0 + cb + nf * 16;         // q
        u16x4 o;
        o.x = f2bf(acc[mf][nf][0] + bv[0]); o.y = f2bf(acc[mf][nf][1] + bv[1]);
        o.z = f2bf(acc[mf][nf][2] + bv[2]); o.w = f2bf(acc[mf][nf][3] + bv[3]);
        *(u16x4*)(dst + (size_t)col * CI_ + row) = o;
      }
    }
  }
}

// ---------------- score (256t, grid (18,18,3), kIters=4) ----------------
__global__ __launch_bounds__(256) void k_score(const u16* TH, const u16* PH,
                                               u16* F, int b) {
  __shared__ char lds[49152];
  const int col0 = blockIdx.x * 128;   // k
  const int row0 = blockIdx.y * 128;   // q
  const int br = blockIdx.z;
  const char* Ab = (const char*)(TH + ((size_t)(br * 4 + b) * N_ + row0) * CI_);
  const char* Bb = (const char*)(PH + ((size_t)(br * 4 + b) * N_ + col0) * CI_);
  f32x4 acc[4][4] = {};
  gemm256c(Ab, 256, Bb, 256, 4, acc, lds);
  EPI_SETUP;
  const int t = (int)threadIdx.x;
  __syncthreads();                      // K-loop LDS reads done; reuse as [128][136]
  u16* tl = (u16*)lds;
  #pragma unroll
  for (int mf = 0; mf < 4; ++mf)
    #pragma unroll
    for (int nf = 0; nf < 4; ++nf)
      #pragma unroll
      for (int r = 0; r < 4; ++r)
        tl[(rb + mf * 16 + r) * 136 + cb + nf * 16] = f2h(acc[mf][nf][r]);
  __syncthreads();
  u16* dst = F + (size_t)br * NN_;
  const int k8 = (t & 15) * 8;
  #pragma unroll
  for (int rr = 0; rr < 8; ++rr) {
    const int q = (t >> 4) + rr * 16;
    *(u16x8*)(dst + (size_t)(row0 + q) * N_ + col0 + k8) =
        *(const u16x8*)(tl + q * 136 + k8);
  }
}

// ---------------- softsum: A-row = sum of 3 softmaxes (no max pass) ----------
__device__ __forceinline__ float blk_sum(float v, float* red) {
  #pragma unroll
  for (int o = 32; o; o >>= 1) v += __shfl_xor(v, o);
  int w = threadIdx.x >> 6;
  __syncthreads();
  if ((threadIdx.x & 63) == 0) red[w] = v;
  __syncthreads();
  return red[0] + red[1] + red[2] + red[3];
}

__global__ __launch_bounds__(256) void k_softsum(const u16* F, u16* Abf, int b) {
  __shared__ float red[4];
  const int q = blockIdx.x, t = threadIdx.x;
  const bool ext = (t < 32);
  float outv[16] = {};
  #pragma unroll
  for (int i = 0; i < 3; ++i) {
    const u16* base = F + (size_t)i * NN_ + (size_t)q * N_;
    float e[16];
    u16x8 a = *(const u16x8*)(base + t * 8);
    #pragma unroll
    for (int jj = 0; jj < 8; ++jj) e[jj] = __expf(h2f(a.e[jj]));
    if (ext) {
      u16x8 c = *(const u16x8*)(base + 2048 + t * 8);
      #pragma unroll
      for (int jj = 0; jj < 8; ++jj) e[8 + jj] = __expf(h2f(c.e[jj]));
    } else {
      #pragma unroll
      for (int jj = 0; jj < 8; ++jj) e[8 + jj] = 0.f;
    }
    float ssum = 0.f;
    #pragma unroll
    for (int s = 0; s < 16; ++s) ssum += e[s];
    ssum = blk_sum(ssum, red);
    const float inv = 1.f / ssum;
    #pragma unroll
    for (int s = 0; s < 16; ++s) outv[s] += e[s] * inv;
  }
  u16* dst = Abf + ((size_t)b * N_ + q) * N_;
  u16x8 o;
  #pragma unroll
  for (int jj = 0; jj < 8; ++jj) o.e[jj] = f2bf(outv[jj]);
  *(u16x8*)(dst + t * 8) = o;
  if (ext) {
    #pragma unroll
    for (int jj = 0; jj < 8; ++jj) o.e[jj] = f2bf(outv[8 + jj]);
    *(u16x8*)(dst + 2048 + t * 8) = o;
  }
}

// ---------------- pv (256t, K-split x2, grid 432, kIters=36) ----------------
__global__ __launch_bounds__(256) void k_pv(const u16* Abf, const u16* GP,
                                            float* P) {
  __shared__ char lds[49152];
  const int lid = xcd_swz();
  const int j = lid % 3;
  const int row0 = ((lid / 3) % 18) * 128; // q
  const int z = lid / 54;
  const int b = z >> 1, s = z & 1;
  const char* Ab = (const char*)(Abf + ((size_t)b * N_ + row0) * N_ + s * 1152);
  const char* Bb = (const char*)(GP + (size_t)(j * 4 + b) * CI_ * N_ + s * 1152);
  f32x4 acc[4][4] = {};
  gemm256c(Ab, 4608, Bb, 4608, 36, acc, lds);
  EPI_SETUP;
  const int t = (int)threadIdx.x;
  float* dst = P + ((size_t)(s * 4 + b) * N_) * 384;
  float* tl = (float*)lds;
  const int jc4 = (t & 15) * 4;
  #pragma unroll
  for (int p = 0; p < 2; ++p) {
    __syncthreads();
    if ((ew & 1) == p) {
      #pragma unroll
      for (int mf = 0; mf < 4; ++mf)
        #pragma unroll
        for (int nf = 0; nf < 4; ++nf)
          #pragma unroll
          for (int r = 0; r < 4; ++r)
            tl[(rb + mf * 16 + r) * 68 + (el & 15) + nf * 16] = acc[mf][nf][r];
    }
    __syncthreads();
    #pragma unroll
    for (int rr = 0; rr < 8; ++rr) {
      const int q = (t >> 4) + rr * 16;
      *(f32x4*)(dst + (size_t)(row0 + q) * 384 + j * 128 + p * 64 + jc4) =
          *(const f32x4*)(tl + q * 68 + jc4);
    }
  }
}

__global__ __launch_bounds__(256) void k_pvred(const float* P, u16* Y) {
  const size_t i4 = (size_t)blockIdx.x * 256 + threadIdx.x;
  constexpr size_t HALF = (size_t)4 * N_ * 384;
  f32x4 a = *(const f32x4*)(P + i4 * 4);
  f32x4 c = *(const f32x4*)(P + HALF + i4 * 4);
  u16x4 o; o.x = f2bf(a[0] + c[0]); o.y = f2bf(a[1] + c[1]);
  o.z = f2bf(a[2] + c[2]); o.w = f2bf(a[3] + c[3]);
  *(u16x4*)(Y + i4 * 4) = o;
}

// ---------------- zcat (256t, grid (18,2,12), kIters=4) ----------------
struct ZA { const float* x[3]; const float* wzb[3]; const float* dww; const float* dwb; };
__global__ __launch_bounds__(256) void k_zcat(const u16* WZ, const u16* Y,
                                              u16* DW, ZA za) {
  __shared__ char lds[49152];
  const int col0 = blockIdx.x * 128;                 // q
  const int row0 = blockIdx.y * 128;                 // c within 256
  const int j = blockIdx.z >> 2, b = blockIdx.z & 3;
  const char* Ab = (const char*)(WZ + (size_t)j * 32768 + (size_t)row0 * CI_);
  const char* Bb = (const char*)(Y + ((size_t)b * N_ + col0) * 384 + j * CI_);
  f32x4 acc[4][4] = {};
  gemm256c(Ab, 256, Bb, 768, 4, acc, lds);
  EPI_SETUP;
  const float* xj = za.x[j];
  #pragma unroll
  for (int mf = 0; mf < 4; ++mf) {
    const int cl = row0 + rb + mf * 16;              // 0..255
    const int cg = j * 256 + cl;
    f32x4 wb = *(const f32x4*)(za.wzb[j] + cl);
    f32x4 sc = *(const f32x4*)(za.dww + cg);
    f32x4 sb = *(const f32x4*)(za.dwb + cg);
    #pragma unroll
    for (int nf = 0; nf < 4; ++nf) {
      const int qg = col0 + cb + nf * 16;
      u16x4 o;
      o.x = f2bf((acc[mf][nf][0] + wb[0] + xj[((size_t)b * C_ + cl + 0) * N_ + qg]) * sc[0] + sb[0]);
      o.y = f2bf((acc[mf][nf][1] + wb[1] + xj[((size_t)b * C_ + cl + 1) * N_ + qg]) * sc[1] + sb[1]);
      o.z = f2bf((acc[mf][nf][2] + wb[2] + xj[((size_t)b * C_ + cl + 2) * N_ + qg]) * sc[2] + sb[2]);
      o.w = f2bf((acc[mf][nf][3] + wb[3] + xj[((size_t)b * C_ + cl + 3) * N_ + qg]) * sc[3] + sb[3]);
      *(u16x4*)(DW + ((size_t)b * N_ + qg) * 768 + cg) = o;
    }
  }
}

// ---------------- final (512t, tile 256x128, depth-4 1-barrier, grid 288) ----
// A = DW q-rows (256), B = pw o-rows (128). Per K-step: stage A 16KB + B 8KB
// (3 gload16/thread), 128 MFMA per block-barrier. vwait<6/6/3/0>.
__global__ __launch_bounds__(512) void k_final(const u16* PWb, const u16* DW,
                                               const float* pwb, const float* xin,
                                               const float* pp, float* out) {
  __shared__ char lds[98304];               // 4 slots x (A 16KB + B 8KB)
  const int lid = xcd_swz();
  const int row0 = (lid % 9) * 256;         // q strip
  const int col0 = ((lid / 9) % 8) * 128;   // o strip
  const int b = lid / 72;
  const char* Ab = (const char*)(DW + ((size_t)b * N_ + row0) * 768);
  const char* Bb = (const char*)(PWb + (size_t)col0 * 768);
  const int t = (int)threadIdx.x, l = t & 63, w = t >> 6;
  const int arow = (w >> 1) * 64 + (l & 15);          // q within 256
  const int brow = (w & 1) * 64 + (l & 15);           // o within 128
  const int kb = ((l >> 4) * 16) ^ ((((l & 15) >> 1) & 3) << 4);
  const float pscale = pp[0];
  // xin prefetch: (o, q-quad) ownership, 1KB-coalesced, issued FIRST.
  const int xq = (t & 63) * 4;              // q within 256
  const int xo = (t >> 6) * 8;              // o within 64-half
  f32x4 xv[2][8];
  #pragma unroll
  for (int p = 0; p < 2; ++p)
    #pragma unroll
    for (int rr = 0; rr < 8; ++rr)
      xv[p][rr] = *(const f32x4*)(
          xin + ((size_t)b * 1024 + col0 + p * 64 + xo + rr) * N_ + row0 + xq);

  // stage: A 256x64B (2 ops/thread) + B 128x64B (1 op/thread), T2-swizzled src
  auto stageF = [&](int kt, char* slot) {
    const char* Ag = Ab + (size_t)kt * 64;
    const char* Bg = Bb + (size_t)kt * 64;
    #pragma unroll
    for (int c = 0; c < 2; ++c) {
      const int idx = (c * 512 + t) * 16;
      const int row = idx >> 6;
      const int gc = (idx & 63) ^ (((row >> 1) & 3) << 4);
      gload16(Ag + (size_t)row * 1536 + gc, slot + idx);
    }
    {
      const int idx = t * 16;
      const int row = idx >> 6;
      const int gc = (idx & 63) ^ (((row >> 1) & 3) << 4);
      gload16(Bg + (size_t)row * 1536 + gc, slot + 16384 + idx);
    }
  };

  f32x4 acc[4][4] = {};
  stageF(0, lds);
  stageF(1, lds + 24576);
  stageF(2, lds + 49152);
  constexpr int KI = 24;
  for (int kt = 0; kt + 4 <= KI; ++kt) {
    char* slot  = lds + (kt & 3) * 24576;
    char* nslot = lds + ((kt + 3) & 3) * 24576;
    vwait<6>();                 // own stage(kt) landed (+xin on kt==0)
    barrier_();                 // all waves' stage(kt) landed; slot (kt+3)&3 dead
    comp32(slot, slot + 16384, acc, arow, brow, kb);
    stageF(kt + 3, nslot);
  }
  { char* slot = lds + ((KI - 3) & 3) * 24576;
    vwait<6>(); barrier_(); comp32(slot, slot + 16384, acc, arow, brow, kb); }
  { char* slot = lds + ((KI - 2) & 3) * 24576;
    vwait<3>(); barrier_(); comp32(slot, slot + 16384, acc, arow, brow, kb); }
  { char* slot = lds + ((KI - 1) & 3) * 24576;
    vwait<0>(); barrier_(); comp32(slot, slot + 16384, acc, arow, brow, kb); }

  // Epilogue: frags -> LDS [64 o][260 q] f32 (2 passes over o-halves),
  // read f32x4 along q -> 1KB-coalesced out stores.
  float* tl = (float*)lds;
  #pragma unroll
  for (int p = 0; p < 2; ++p) {
    __syncthreads();
    if ((w & 1) == p) {                     // wave-columns owning o-half p
      #pragma unroll
      for (int mf = 0; mf < 4; ++mf)
        #pragma unroll
        for (int nf = 0; nf < 4; ++nf)
          #pragma unroll
          for (int r = 0; r < 4; ++r)
            tl[((l & 15) + nf * 16) * 260 + arow - (l & 15) + mf * 16 +
               ((l >> 4) << 2) + r - ((w >> 1) * 64) + (w >> 1) * 64] =
                acc[mf][nf][r];
    }
    __syncthreads();
    #pragma unroll
    for (int rr = 0; rr < 8; ++rr) {
      const int og = col0 + p * 64 + xo + rr;
      const float bb = pwb[og];
      f32x4 a4 = *(const f32x4*)(tl + (xo + rr) * 260 + xq);
      f32x4 o4;
      #pragma unroll
      for (int r = 0; r < 4; ++r)
        o4[r] = xv[p][rr][r] + pscale * (a4[r] + bb);
      *(f32x4*)(out + ((size_t)b * 1024 + og) * N_ + row0 + xq) = o4;
    }
  }
}

// ---------------------------------------------------------------------------
extern "C" void kernel_launch(void* const* d_in, const int* in_sizes, int n_in,
                              void* d_out, int out_size, void* d_ws, size_t ws_size,
                              hipStream_t stream) {
  const float* x0  = (const float*)d_in[0];
  const float* x1  = (const float*)d_in[1];
  const float* x2  = (const float*)d_in[2];
  const float* xin = (const float*)d_in[3];
  const float* g_w = (const float*)d_in[4];
  const float* g_b = (const float*)d_in[5];
  const float* thw[3] = {(const float*)d_in[6],  (const float*)d_in[10], (const float*)d_in[14]};
  const float* thb[3] = {(const float*)d_in[7],  (const float*)d_in[11], (const float*)d_in[15]};
  const float* phw[3] = {(const float*)d_in[8],  (const float*)d_in[12], (const float*)d_in[16]};
  const float* phb[3] = {(const float*)d_in[9],  (const float*)d_in[13], (const float*)d_in[17]};
  const float* Wm[3]  = {(const float*)d_in[18], (const float*)d_in[20], (const float*)d_in[22]};
  const float* Wmb[3] = {(const float*)d_in[19], (const float*)d_in[21], (const float*)d_in[23]};
  const float* dww = (const float*)d_in[24];
  const float* dwb = (const float*)d_in[25];
  const float* pww = (const float*)d_in[26];
  const float* pwb = (const float*)d_in[27];
  const float* pp  = (const float*)d_in[28];

  char* wsb = (char*)d_ws;
  u16*   WB  = (u16*)(wsb + B_WB);
  u16*   WZ  = (u16*)(wsb + B_WZ);
  u16*   PW  = (u16*)(wsb + B_PW);
  u16*   XT  = (u16*)(wsb + B_R1);
  u16*   Y   = (u16*)(wsb + B_R1);   // overlays XT (dead after k_proj)
  u16*   TH  = (u16*)(wsb + B_R2);
  u16*   PH  = TH + (size_t)3 * B_ * N_ * CI_;
  u16*   DW  = (u16*)(wsb + B_R2);   // overlays TH/PH (dead after last k_score)
  u16*   GP  = (u16*)(wsb + B_GP);
  u16*   Fh  = (u16*)(wsb + B_F);    // fp16 scores, per batch
  float* Pp  = (float*)(wsb + B_F);  // pv partials overlay (Fh dead after softsum)
  u16*   Abf = (u16*)(wsb + B_A);

  CvtW cw;
  cw.s[0] = g_w; cw.s[1] = thw[0]; cw.s[2] = phw[0];
  cw.s[3] = g_w; cw.s[4] = thw[1]; cw.s[5] = phw[1];
  cw.s[6] = g_w; cw.s[7] = thw[2]; cw.s[8] = phw[2];
  cw.s[9] = Wm[0]; cw.s[10] = Wm[1]; cw.s[11] = Wm[2];
  cw.s[12] = pww;

  ProjA pa;
  pa.bias[0] = g_b; pa.bias[1] = thb[0]; pa.bias[2] = phb[0];
  pa.bias[3] = g_b; pa.bias[4] = thb[1]; pa.bias[5] = phb[1];
  pa.bias[6] = g_b; pa.bias[7] = thb[2]; pa.bias[8] = phb[2];

  ZA za;
  za.x[0] = x0; za.x[1] = x1; za.x[2] = x2;
  za.wzb[0] = Wmb[0]; za.wzb[1] = Wmb[1]; za.wzb[2] = Wmb[2];
  za.dww = dww; za.dwb = dwb;

  k_cvtw<<<dim3(768, 13), 256, 0, stream>>>(cw, WB);
  k_cvtx<<<dim3(36, 4, 12), 256, 0, stream>>>(x0, x1, x2, XT);
  k_proj<<<dim3(18, 1, 36), 256, 0, stream>>>(WB, XT, TH, PH, GP, pa);
  for (int b = 0; b < B_; ++b) {
    k_score  <<<dim3(18, 18, 3), 256, 0, stream>>>(TH, PH, Fh, b);
    k_softsum<<<dim3(N_),        256, 0, stream>>>(Fh, Abf, b);
  }
  k_pv   <<<dim3(432),  256, 0, stream>>>(Abf, GP, Pp);
  k_pvred<<<dim3(3456), 256, 0, stream>>>(Pp, Y);
  k_zcat <<<dim3(18, 2, 12), 256, 0, stream>>>(WZ, Y, DW, za);
  k_final<<<dim3(288),  512, 0, stream>>>(PW, DW, pwb, xin, pp, (float*)d_out);
}

// Round 13
// 211.351 us; speedup vs baseline: 1.0240x; 1.0198x over previous
//
#include <hip/hip_runtime.h>

// ---------------------------------------------------------------------------
// NonLocalBlockND — bf16 MFMA pipeline, round 13 = exact revert to round 10,
// the best measured configuration (210.07 us).
//
// Final configuration (per-kernel):
//   * Uniform 256-thread GEMM core: 128x128 tile, BK=32, depth-3 LDS ring
//     (48 KB -> 3 blocks/CU), counted s_waitcnt vmcnt(8/4/0) + raw barriers,
//     T2 both-sides XOR swizzle (S(row)=((row>>1)&3)<<4; conflicts = 0),
//     s_setprio(1) around the MFMA cluster.
//   * k_score / k_pv / k_final: LDS-transpose epilogues (coalesced stores).
//   * k_final: A=DW q-rows, B=pw o-rows; xin f32x4 register prefetch issued
//     oldest (drained by the first vmcnt(8)); grid 576, XCD-chunk swizzled.
//   * k_pv: K-split x2 into f32 partials + k_pvred; grid 432, swizzled.
//   * k_softsum: no-max softmax (scores sigma~7.2, fp32 exp safe), u16x8 IO.
//
// Structure ceiling note (R7-R12 sweep): occupancy, MLP depth, bank
// conflicts, store coalescing, barrier count, and tile shape were each
// isolated; the large GEMMs pin at ~300-360 TF, matching the guide's m102
// measured curve for the 128^2-class structure at these shapes. The 8-phase
// 256^2 template's prerequisites (>=256 blocks of 256^2, deep K) are not
// satisfiable for this problem's shapes.
//
// ws layout (112,066,560 bytes <= proven budget).
// ---------------------------------------------------------------------------

typedef __attribute__((ext_vector_type(8))) short bf16x8;
typedef __attribute__((ext_vector_type(4))) float f32x4;
typedef unsigned short u16;
struct alignas(8) u16x4 { u16 x, y, z, w; };
struct alignas(16) u16x8 { u16 e[8]; };

constexpr int B_ = 4, C_ = 256, N_ = 2304, CI_ = 128;
constexpr long long NN_ = (long long)N_ * N_;

constexpr size_t B_WB = 0;
constexpr size_t B_WZ = 589824;
constexpr size_t B_PW = 786432;
constexpr size_t B_R1 = 2359296;
constexpr size_t B_R2 = 16515072;
constexpr size_t B_GP = 30670848;
constexpr size_t B_F  = 37748736;
constexpr size_t B_A  = 69599232;

__device__ __forceinline__ u16 f2bf(float f) {
  unsigned u = __float_as_uint(f);
  u += 0x7fff + ((u >> 16) & 1);
  return (u16)(u >> 16);
}
__device__ __forceinline__ u16 f2h(float f) {
  _Float16 h = (_Float16)f;
  return __builtin_bit_cast(u16, h);
}
__device__ __forceinline__ float h2f(u16 u) {
  return (float)__builtin_bit_cast(_Float16, u);
}

__device__ __forceinline__ void gload16(const void* g, void* l) {
  __builtin_amdgcn_global_load_lds((const __attribute__((address_space(1))) void*)g,
                                   (__attribute__((address_space(3))) void*)l,
                                   16, 0, 0);
}

template<int N> __device__ __forceinline__ void vwait() {
  asm volatile("s_waitcnt vmcnt(%0)" :: "i"(N) : "memory");
}
__device__ __forceinline__ void barrier_() {
  asm volatile("" ::: "memory");
  __builtin_amdgcn_s_barrier();
  asm volatile("" ::: "memory");
}

// m204 bijective XCD-chunk swizzle (grid % 8 == 0 for all users).
__device__ __forceinline__ int xcd_swz() {
  const int nwg = (int)gridDim.x, orig = (int)blockIdx.x;
  const int q = nwg >> 3, r = nwg & 7;
  const int xcd = orig & 7, pos = orig >> 3;
  return (xcd < r ? xcd * (q + 1) : r * (q + 1) + (xcd - r) * q) + pos;
}

// ========== uniform 256-thread core: 128x128 tile, BK=32, depth-3 ring =======
// T2 swizzle: S(row) = ((row>>1)&3)<<4 permutes the four 16B slots of each
// 64B LDS row. Stage pre-swizzles the GLOBAL source col; reads XOR kb.
__device__ __forceinline__ void stage32(const char* Ag, int ldaB,
                                        const char* Bg, int ldbB,
                                        char* As, char* Bs, int t) {
  #pragma unroll
  for (int c = 0; c < 2; ++c) {
    const int idx = (c * 256 + t) * 16;
    const int row = idx >> 6;
    const int gc = (idx & 63) ^ (((row >> 1) & 3) << 4);
    gload16(Ag + (size_t)row * ldaB + gc, As + idx);
    gload16(Bg + (size_t)row * ldbB + gc, Bs + idx);
  }
}

// One BK=32 K-step; kb arrives pre-XORed with S(l&15).
__device__ __forceinline__ void comp32(const char* As, const char* Bs,
                                       f32x4 (&acc)[4][4],
                                       int arow, int brow, int kb) {
  bf16x8 af[4], bfr[4];
  #pragma unroll
  for (int i = 0; i < 4; ++i) {
    af[i]  = *(const bf16x8*)(As + (arow + i * 16) * 64 + kb);
    bfr[i] = *(const bf16x8*)(Bs + (brow + i * 16) * 64 + kb);
  }
  __builtin_amdgcn_s_setprio(1);
  #pragma unroll
  for (int mf = 0; mf < 4; ++mf)
    #pragma unroll
    for (int nf = 0; nf < 4; ++nf)
      acc[mf][nf] = __builtin_amdgcn_mfma_f32_16x16x32_bf16(
          af[mf], bfr[nf], acc[mf][nf], 0, 0, 0);
  __builtin_amdgcn_s_setprio(0);
}

// Depth-3 counted vmcnt; requires kIters >= 3 (all users >= 4).
__device__ __forceinline__ void gemm256c(const char* Ab, int ldaB,
                                         const char* Bb, int ldbB,
                                         int kIters, f32x4 (&acc)[4][4],
                                         char* lds) {
  const int t = (int)threadIdx.x, l = t & 63, w = t >> 6;
  const int arow = (w >> 1) * 64 + (l & 15);
  const int brow = (w & 1) * 64 + (l & 15);
  const int kb = ((l >> 4) * 16) ^ ((((l & 15) >> 1) & 3) << 4);
  char* A0 = lds;          char* B0 = lds + 8192;
  char* A1 = lds + 16384;  char* B1 = lds + 24576;
  char* A2 = lds + 32768;  char* B2 = lds + 40960;
  stage32(Ab,      ldaB, Bb,      ldbB, A0, B0, t);
  stage32(Ab + 64, ldaB, Bb + 64, ldbB, A1, B1, t);
  for (int kt = 0; kt < kIters - 2; ++kt) {
    stage32(Ab + (size_t)(kt + 2) * 64, ldaB,
            Bb + (size_t)(kt + 2) * 64, ldbB, A2, B2, t);
    vwait<8>();
    barrier_();
    comp32(A0, B0, acc, arow, brow, kb);
    barrier_();
    char* ta = A0; A0 = A1; A1 = A2; A2 = ta;
    char* tb = B0; B0 = B1; B1 = B2; B2 = tb;
  }
  vwait<4>();
  barrier_();
  comp32(A0, B0, acc, arow, brow, kb);
  vwait<0>();
  barrier_();
  comp32(A1, B1, acc, arow, brow, kb);
}

#define EPI_SETUP \
  const int el = (int)threadIdx.x & 63, ew = (int)threadIdx.x >> 6; \
  const int rb = (ew >> 1) * 64 + ((el >> 4) << 2); \
  const int cb = (ew & 1) * 64 + (el & 15);

// ---------------- weight convert ----------------
struct CvtW { const float* s[13]; };
__global__ __launch_bounds__(256) void k_cvtw(CvtW cw, u16* dst) {
  const int seg = blockIdx.y;
  const int i = (blockIdx.x * 256 + threadIdx.x) * 4;
  const int sz = (seg == 12) ? 786432 : 32768;
  if (i >= sz) return;
  size_t off = (seg < 9) ? (size_t)seg * 32768
             : (seg < 12) ? 294912 + (size_t)(seg - 9) * 32768
                          : 393216;
  f32x4 v = *(const f32x4*)(cw.s[seg] + i);
  u16x4 o; o.x = f2bf(v[0]); o.y = f2bf(v[1]); o.z = f2bf(v[2]); o.w = f2bf(v[3]);
  *(u16x4*)(dst + off + i) = o;
}

// ---------------- x transpose-convert: (b,c,n) -> xbT[vb][q][c] ----------------
__global__ __launch_bounds__(256) void k_cvtx(const float* x0, const float* x1,
                                              const float* x2, u16* XT) {
  __shared__ float tile[64][65];
  const int t = threadIdx.x;
  const int q0 = blockIdx.x * 64, c0 = blockIdx.y * 64;
  const int vb = blockIdx.z, v = vb >> 2, b = vb & 3;
  const float* src = (v == 0 ? x0 : v == 1 ? x1 : x2) + ((size_t)b * C_ + c0) * N_ + q0;
  #pragma unroll
  for (int i = 0; i < 4; ++i) {
    int idx = t + i * 256;
    int r = idx >> 4, q4 = (idx & 15) * 4;
    f32x4 val = *(const f32x4*)(src + (size_t)r * N_ + q4);
    tile[r][q4 + 0] = val[0]; tile[r][q4 + 1] = val[1];
    tile[r][q4 + 2] = val[2]; tile[r][q4 + 3] = val[3];
  }
  __syncthreads();
  u16* dst = XT + ((size_t)vb * N_ + q0) * 256 + c0;
  const int q = t >> 2, cp = (t & 3) * 16;
  u16 tmp[16];
  #pragma unroll
  for (int jj = 0; jj < 16; ++jj) tmp[jj] = f2bf(tile[cp + jj][q]);
  #pragma unroll
  for (int s4 = 0; s4 < 4; ++s4) {
    u16x4 o; o.x = tmp[s4 * 4]; o.y = tmp[s4 * 4 + 1];
    o.z = tmp[s4 * 4 + 2]; o.w = tmp[s4 * 4 + 3];
    *(u16x4*)(dst + (size_t)q * 256 + cp + s4 * 4) = o;
  }
}

// ---------------- proj (256t, grid (18,1,36), kIters=8) ----------------
struct ProjA { const float* bias[9]; };
__global__ __launch_bounds__(256) void k_proj(const u16* WB, const u16* XT,
                                              u16* TH, u16* PH, u16* GP, ProjA pa) {
  __shared__ char lds[49152];
  const int col0 = blockIdx.x * 128;                 // q
  const int p = blockIdx.z >> 2, b = blockIdx.z & 3;
  const int v = p / 3, pt = p % 3;
  const char* Ab = (const char*)(WB + (size_t)p * 32768);
  const char* Bb = (const char*)(XT + ((size_t)(v * 4 + b) * N_ + col0) * 256);
  f32x4 acc[4][4] = {};
  gemm256c(Ab, 512, Bb, 512, 8, acc, lds);
  EPI_SETUP;
  const float* bias = pa.bias[p];
  if (pt == 0) {                                     // g -> (ci, m) natural
    u16* dst = GP + (size_t)(v * 4 + b) * CI_ * N_;
    #pragma unroll
    for (int mf = 0; mf < 4; ++mf) {
      const int row = rb + mf * 16;
      f32x4 bv = *(const f32x4*)(bias + row);
      #pragma unroll
      for (int nf = 0; nf < 4; ++nf) {
        const int col = col0 + cb + nf * 16;
        #pragma unroll
        for (int r = 0; r < 4; ++r)
          dst[(size_t)(row + r) * N_ + col] = f2bf(acc[mf][nf][r] + bv[r]);
      }
    }
  } else {                                           // theta/phi -> (q, ci)
    u16* dst = (pt == 1 ? TH : PH) + (size_t)(v * 4 + b) * N_ * CI_;
    #pragma unroll
    for (int mf = 0; mf < 4; ++mf) {
      const int row = rb + mf * 16;                  // ci
      f32x4 bv = *(const f32x4*)(bias + row);
      #pragma unroll
      for (int nf = 0; nf < 4; ++nf) {
        const int col = col0 + cb + nf * 16;         // q
        u16x4 o;
        o.x = f2bf(acc[mf][nf][0] + bv[0]); o.y = f2bf(acc[mf][nf][1] + bv[1]);
        o.z = f2bf(acc[mf][nf][2] + bv[2]); o.w = f2bf(acc[mf][nf][3] + bv[3]);
        *(u16x4*)(dst + (size_t)col * CI_ + row) = o;
      }
    }
  }
}

// ---------------- score (256t, grid (18,18,3), kIters=4) ----------------
__global__ __launch_bounds__(256) void k_score(const u16* TH, const u16* PH,
                                               u16* F, int b) {
  __shared__ char lds[49152];
  const int col0 = blockIdx.x * 128;   // k
  const int row0 = blockIdx.y * 128;   // q
  const int br = blockIdx.z;
  const char* Ab = (const char*)(TH + ((size_t)(br * 4 + b) * N_ + row0) * CI_);
  const char* Bb = (const char*)(PH + ((size_t)(br * 4 + b) * N_ + col0) * CI_);
  f32x4 acc[4][4] = {};
  gemm256c(Ab, 256, Bb, 256, 4, acc, lds);
  EPI_SETUP;
  const int t = (int)threadIdx.x;
  __syncthreads();                      // K-loop LDS reads done; reuse as [128][136]
  u16* tl = (u16*)lds;
  #pragma unroll
  for (int mf = 0; mf < 4; ++mf)
    #pragma unroll
    for (int nf = 0; nf < 4; ++nf)
      #pragma unroll
      for (int r = 0; r < 4; ++r)
        tl[(rb + mf * 16 + r) * 136 + cb + nf * 16] = f2h(acc[mf][nf][r]);
  __syncthreads();
  u16* dst = F + (size_t)br * NN_;
  const int k8 = (t & 15) * 8;
  #pragma unroll
  for (int rr = 0; rr < 8; ++rr) {
    const int q = (t >> 4) + rr * 16;
    *(u16x8*)(dst + (size_t)(row0 + q) * N_ + col0 + k8) =
        *(const u16x8*)(tl + q * 136 + k8);
  }
}

// ---------------- softsum: A-row = sum of 3 softmaxes (no max pass) ----------
__device__ __forceinline__ float blk_sum(float v, float* red) {
  #pragma unroll
  for (int o = 32; o; o >>= 1) v += __shfl_xor(v, o);
  int w = threadIdx.x >> 6;
  __syncthreads();
  if ((threadIdx.x & 63) == 0) red[w] = v;
  __syncthreads();
  return red[0] + red[1] + red[2] + red[3];
}

__global__ __launch_bounds__(256) void k_softsum(const u16* F, u16* Abf, int b) {
  __shared__ float red[4];
  const int q = blockIdx.x, t = threadIdx.x;
  const bool ext = (t < 32);
  float outv[16] = {};
  #pragma unroll
  for (int i = 0; i < 3; ++i) {
    const u16* base = F + (size_t)i * NN_ + (size_t)q * N_;
    float e[16];
    u16x8 a = *(const u16x8*)(base + t * 8);
    #pragma unroll
    for (int jj = 0; jj < 8; ++jj) e[jj] = __expf(h2f(a.e[jj]));
    if (ext) {
      u16x8 c = *(const u16x8*)(base + 2048 + t * 8);
      #pragma unroll
      for (int jj = 0; jj < 8; ++jj) e[8 + jj] = __expf(h2f(c.e[jj]));
    } else {
      #pragma unroll
      for (int jj = 0; jj < 8; ++jj) e[8 + jj] = 0.f;
    }
    float ssum = 0.f;
    #pragma unroll
    for (int s = 0; s < 16; ++s) ssum += e[s];
    ssum = blk_sum(ssum, red);
    const float inv = 1.f / ssum;
    #pragma unroll
    for (int s = 0; s < 16; ++s) outv[s] += e[s] * inv;
  }
  u16* dst = Abf + ((size_t)b * N_ + q) * N_;
  u16x8 o;
  #pragma unroll
  for (int jj = 0; jj < 8; ++jj) o.e[jj] = f2bf(outv[jj]);
  *(u16x8*)(dst + t * 8) = o;
  if (ext) {
    #pragma unroll
    for (int jj = 0; jj < 8; ++jj) o.e[jj] = f2bf(outv[8 + jj]);
    *(u16x8*)(dst + 2048 + t * 8) = o;
  }
}

// ---------------- pv (256t, K-split x2, grid 432, kIters=36) ----------------
__global__ __launch_bounds__(256) void k_pv(const u16* Abf, const u16* GP,
                                            float* P) {
  __shared__ char lds[49152];
  const int lid = xcd_swz();
  const int j = lid % 3;
  const int row0 = ((lid / 3) % 18) * 128; // q
  const int z = lid / 54;
  const int b = z >> 1, s = z & 1;
  const char* Ab = (const char*)(Abf + ((size_t)b * N_ + row0) * N_ + s * 1152);
  const char* Bb = (const char*)(GP + (size_t)(j * 4 + b) * CI_ * N_ + s * 1152);
  f32x4 acc[4][4] = {};
  gemm256c(Ab, 4608, Bb, 4608, 36, acc, lds);
  EPI_SETUP;
  const int t = (int)threadIdx.x;
  float* dst = P + ((size_t)(s * 4 + b) * N_) * 384;
  float* tl = (float*)lds;
  const int jc4 = (t & 15) * 4;
  #pragma unroll
  for (int p = 0; p < 2; ++p) {
    __syncthreads();
    if ((ew & 1) == p) {
      #pragma unroll
      for (int mf = 0; mf < 4; ++mf)
        #pragma unroll
        for (int nf = 0; nf < 4; ++nf)
          #pragma unroll
          for (int r = 0; r < 4; ++r)
            tl[(rb + mf * 16 + r) * 68 + (el & 15) + nf * 16] = acc[mf][nf][r];
    }
    __syncthreads();
    #pragma unroll
    for (int rr = 0; rr < 8; ++rr) {
      const int q = (t >> 4) + rr * 16;
      *(f32x4*)(dst + (size_t)(row0 + q) * 384 + j * 128 + p * 64 + jc4) =
          *(const f32x4*)(tl + q * 68 + jc4);
    }
  }
}

__global__ __launch_bounds__(256) void k_pvred(const float* P, u16* Y) {
  const size_t i4 = (size_t)blockIdx.x * 256 + threadIdx.x;
  constexpr size_t HALF = (size_t)4 * N_ * 384;
  f32x4 a = *(const f32x4*)(P + i4 * 4);
  f32x4 c = *(const f32x4*)(P + HALF + i4 * 4);
  u16x4 o; o.x = f2bf(a[0] + c[0]); o.y = f2bf(a[1] + c[1]);
  o.z = f2bf(a[2] + c[2]); o.w = f2bf(a[3] + c[3]);
  *(u16x4*)(Y + i4 * 4) = o;
}

// ---------------- zcat (256t, grid (18,2,12), kIters=4) ----------------
struct ZA { const float* x[3]; const float* wzb[3]; const float* dww; const float* dwb; };
__global__ __launch_bounds__(256) void k_zcat(const u16* WZ, const u16* Y,
                                              u16* DW, ZA za) {
  __shared__ char lds[49152];
  const int col0 = blockIdx.x * 128;                 // q
  const int row0 = blockIdx.y * 128;                 // c within 256
  const int j = blockIdx.z >> 2, b = blockIdx.z & 3;
  const char* Ab = (const char*)(WZ + (size_t)j * 32768 + (size_t)row0 * CI_);
  const char* Bb = (const char*)(Y + ((size_t)b * N_ + col0) * 384 + j * CI_);
  f32x4 acc[4][4] = {};
  gemm256c(Ab, 256, Bb, 768, 4, acc, lds);
  EPI_SETUP;
  const float* xj = za.x[j];
  #pragma unroll
  for (int mf = 0; mf < 4; ++mf) {
    const int cl = row0 + rb + mf * 16;              // 0..255
    const int cg = j * 256 + cl;
    f32x4 wb = *(const f32x4*)(za.wzb[j] + cl);
    f32x4 sc = *(const f32x4*)(za.dww + cg);
    f32x4 sb = *(const f32x4*)(za.dwb + cg);
    #pragma unroll
    for (int nf = 0; nf < 4; ++nf) {
      const int qg = col0 + cb + nf * 16;
      u16x4 o;
      o.x = f2bf((acc[mf][nf][0] + wb[0] + xj[((size_t)b * C_ + cl + 0) * N_ + qg]) * sc[0] + sb[0]);
      o.y = f2bf((acc[mf][nf][1] + wb[1] + xj[((size_t)b * C_ + cl + 1) * N_ + qg]) * sc[1] + sb[1]);
      o.z = f2bf((acc[mf][nf][2] + wb[2] + xj[((size_t)b * C_ + cl + 2) * N_ + qg]) * sc[2] + sb[2]);
      o.w = f2bf((acc[mf][nf][3] + wb[3] + xj[((size_t)b * C_ + cl + 3) * N_ + qg]) * sc[3] + sb[3]);
      *(u16x4*)(DW + ((size_t)b * N_ + qg) * 768 + cg) = o;
    }
  }
}

// ---------------- final (256t, grid 576 swizzled, kIters=24) -----------------
__global__ __launch_bounds__(256) void k_final(const u16* PWb, const u16* DW,
                                               const float* pwb, const float* xin,
                                               const float* pp, float* out) {
  __shared__ char lds[49152];
  const int lid = xcd_swz();
  const int row0 = (lid % 18) * 128;        // q strip
  const int col0 = ((lid / 18) % 8) * 128;  // o strip
  const int b = lid / 144;
  const char* Ab = (const char*)(DW + ((size_t)b * N_ + row0) * 768);
  const char* Bb = (const char*)(PWb + (size_t)col0 * 768);
  EPI_SETUP;
  const int t = (int)threadIdx.x;
  const float pscale = pp[0];
  const int q4 = (t & 31) * 4;
  const int ob = (t >> 5) * 8;
  f32x4 xv[2][8];
  #pragma unroll
  for (int p = 0; p < 2; ++p)
    #pragma unroll
    for (int rr = 0; rr < 8; ++rr)
      xv[p][rr] = *(const f32x4*)(
          xin + ((size_t)b * 1024 + col0 + p * 64 + ob + rr) * N_ + row0 + q4);
  f32x4 acc[4][4] = {};
  gemm256c(Ab, 1536, Bb, 1536, 24, acc, lds);
  float* tl = (float*)lds;
  #pragma unroll
  for (int p = 0; p < 2; ++p) {
    __syncthreads();
    if ((ew & 1) == p) {                   // this wave-column owns o-half p
      #pragma unroll
      for (int mf = 0; mf < 4; ++mf)
        #pragma unroll
        for (int nf = 0; nf < 4; ++nf)
          #pragma unroll
          for (int r = 0; r < 4; ++r)
            tl[((el & 15) + nf * 16) * 132 + rb + mf * 16 + r] = acc[mf][nf][r];
    }
    __syncthreads();
    #pragma unroll
    for (int rr = 0; rr < 8; ++rr) {
      const int og = col0 + p * 64 + ob + rr;
      const float bb = pwb[og];
      f32x4 a4 = *(const f32x4*)(tl + (ob + rr) * 132 + q4);
      f32x4 o4;
      #pragma unroll
      for (int r = 0; r < 4; ++r)
        o4[r] = xv[p][rr][r] + pscale * (a4[r] + bb);
      *(f32x4*)(out + ((size_t)b * 1024 + og) * N_ + row0 + q4) = o4;
    }
  }
}

// ---------------------------------------------------------------------------
extern "C" void kernel_launch(void* const* d_in, const int* in_sizes, int n_in,
                              void* d_out, int out_size, void* d_ws, size_t ws_size,
                              hipStream_t stream) {
  const float* x0  = (const float*)d_in[0];
  const float* x1  = (const float*)d_in[1];
  const float* x2  = (const float*)d_in[2];
  const float* xin = (const float*)d_in[3];
  const float* g_w = (const float*)d_in[4];
  const float* g_b = (const float*)d_in[5];
  const float* thw[3] = {(const float*)d_in[6],  (const float*)d_in[10], (const float*)d_in[14]};
  const float* thb[3] = {(const float*)d_in[7],  (const float*)d_in[11], (const float*)d_in[15]};
  const float* phw[3] = {(const float*)d_in[8],  (const float*)d_in[12], (const float*)d_in[16]};
  const float* phb[3] = {(const float*)d_in[9],  (const float*)d_in[13], (const float*)d_in[17]};
  const float* Wm[3]  = {(const float*)d_in[18], (const float*)d_in[20], (const float*)d_in[22]};
  const float* Wmb[3] = {(const float*)d_in[19], (const float*)d_in[21], (const float*)d_in[23]};
  const float* dww = (const float*)d_in[24];
  const float* dwb = (const float*)d_in[25];
  const float* pww = (const float*)d_in[26];
  const float* pwb = (const float*)d_in[27];
  const float* pp  = (const float*)d_in[28];

  char* wsb = (char*)d_ws;
  u16*   WB  = (u16*)(wsb + B_WB);
  u16*   WZ  = (u16*)(wsb + B_WZ);
  u16*   PW  = (u16*)(wsb + B_PW);
  u16*   XT  = (u16*)(wsb + B_R1);
  u16*   Y   = (u16*)(wsb + B_R1);   // overlays XT (dead after k_proj)
  u16*   TH  = (u16*)(wsb + B_R2);
  u16*   PH  = TH + (size_t)3 * B_ * N_ * CI_;
  u16*   DW  = (u16*)(wsb + B_R2);   // overlays TH/PH (dead after last k_score)
  u16*   GP  = (u16*)(wsb + B_GP);
  u16*   Fh  = (u16*)(wsb + B_F);    // fp16 scores, per batch
  float* Pp  = (float*)(wsb + B_F);  // pv partials overlay (Fh dead after softsum)
  u16*   Abf = (u16*)(wsb + B_A);

  CvtW cw;
  cw.s[0] = g_w; cw.s[1] = thw[0]; cw.s[2] = phw[0];
  cw.s[3] = g_w; cw.s[4] = thw[1]; cw.s[5] = phw[1];
  cw.s[6] = g_w; cw.s[7] = thw[2]; cw.s[8] = phw[2];
  cw.s[9] = Wm[0]; cw.s[10] = Wm[1]; cw.s[11] = Wm[2];
  cw.s[12] = pww;

  ProjA pa;
  pa.bias[0] = g_b; pa.bias[1] = thb[0]; pa.bias[2] = phb[0];
  pa.bias[3] = g_b; pa.bias[4] = thb[1]; pa.bias[5] = phb[1];
  pa.bias[6] = g_b; pa.bias[7] = thb[2]; pa.bias[8] = phb[2];

  ZA za;
  za.x[0] = x0; za.x[1] = x1; za.x[2] = x2;
  za.wzb[0] = Wmb[0]; za.wzb[1] = Wmb[1]; za.wzb[2] = Wmb[2];
  za.dww = dww; za.dwb = dwb;

  k_cvtw<<<dim3(768, 13), 256, 0, stream>>>(cw, WB);
  k_cvtx<<<dim3(36, 4, 12), 256, 0, stream>>>(x0, x1, x2, XT);
  k_proj<<<dim3(18, 1, 36), 256, 0, stream>>>(WB, XT, TH, PH, GP, pa);
  for (int b = 0; b < B_; ++b) {
    k_score  <<<dim3(18, 18, 3), 256, 0, stream>>>(TH, PH, Fh, b);
    k_softsum<<<dim3(N_),        256, 0, stream>>>(Fh, Abf, b);
  }
  k_pv   <<<dim3(432),  256, 0, stream>>>(Abf, GP, Pp);
  k_pvred<<<dim3(3456), 256, 0, stream>>>(Pp, Y);
  k_zcat <<<dim3(18, 2, 12), 256, 0, stream>>>(WZ, Y, DW, za);
  k_final<<<dim3(576),  256, 0, stream>>>(PW, DW, pwb, xin, pp, (float*)d_out);
}

// Round 14
// 204.165 us; speedup vs baseline: 1.0601x; 1.0352x over previous
//
#include <hip/hip_runtime.h>

// ---------------------------------------------------------------------------
// NonLocalBlockND — bf16 MFMA pipeline, round 14 = round 13 (best config,
// 210-211 us) + three non-GEMM micro-optimizations:
//  * k_pv partials stored bf16 (was f32): halves the partial round-trip
//    (28.3+28.3 MB -> 14.2+14.2 MB). LDS-transpose epilogue in u16, stride 72.
//  * k_pvred: u16x8 IO, 8 elems/thread, grid 1728.
//  * k_softsum: fused 3-way block reduction (one barrier pair instead of
//    three; 18 shfl instead of 54).
// GEMM cores, grids, layouts identical to round 13.
// ws layout unchanged (112,066,560 bytes).
// ---------------------------------------------------------------------------

typedef __attribute__((ext_vector_type(8))) short bf16x8;
typedef __attribute__((ext_vector_type(4))) float f32x4;
typedef unsigned short u16;
struct alignas(8) u16x4 { u16 x, y, z, w; };
struct alignas(16) u16x8 { u16 e[8]; };

constexpr int B_ = 4, C_ = 256, N_ = 2304, CI_ = 128;
constexpr long long NN_ = (long long)N_ * N_;

constexpr size_t B_WB = 0;
constexpr size_t B_WZ = 589824;
constexpr size_t B_PW = 786432;
constexpr size_t B_R1 = 2359296;
constexpr size_t B_R2 = 16515072;
constexpr size_t B_GP = 30670848;
constexpr size_t B_F  = 37748736;
constexpr size_t B_A  = 69599232;

__device__ __forceinline__ u16 f2bf(float f) {
  unsigned u = __float_as_uint(f);
  u += 0x7fff + ((u >> 16) & 1);
  return (u16)(u >> 16);
}
__device__ __forceinline__ float bf2f(u16 u) {
  return __uint_as_float((unsigned)u << 16);
}
__device__ __forceinline__ u16 f2h(float f) {
  _Float16 h = (_Float16)f;
  return __builtin_bit_cast(u16, h);
}
__device__ __forceinline__ float h2f(u16 u) {
  return (float)__builtin_bit_cast(_Float16, u);
}

__device__ __forceinline__ void gload16(const void* g, void* l) {
  __builtin_amdgcn_global_load_lds((const __attribute__((address_space(1))) void*)g,
                                   (__attribute__((address_space(3))) void*)l,
                                   16, 0, 0);
}

template<int N> __device__ __forceinline__ void vwait() {
  asm volatile("s_waitcnt vmcnt(%0)" :: "i"(N) : "memory");
}
__device__ __forceinline__ void barrier_() {
  asm volatile("" ::: "memory");
  __builtin_amdgcn_s_barrier();
  asm volatile("" ::: "memory");
}

// m204 bijective XCD-chunk swizzle (grid % 8 == 0 for all users).
__device__ __forceinline__ int xcd_swz() {
  const int nwg = (int)gridDim.x, orig = (int)blockIdx.x;
  const int q = nwg >> 3, r = nwg & 7;
  const int xcd = orig & 7, pos = orig >> 3;
  return (xcd < r ? xcd * (q + 1) : r * (q + 1) + (xcd - r) * q) + pos;
}

// ========== uniform 256-thread core: 128x128 tile, BK=32, depth-3 ring =======
// T2 swizzle: S(row) = ((row>>1)&3)<<4 permutes the four 16B slots of each
// 64B LDS row. Stage pre-swizzles the GLOBAL source col; reads XOR kb.
__device__ __forceinline__ void stage32(const char* Ag, int ldaB,
                                        const char* Bg, int ldbB,
                                        char* As, char* Bs, int t) {
  #pragma unroll
  for (int c = 0; c < 2; ++c) {
    const int idx = (c * 256 + t) * 16;
    const int row = idx >> 6;
    const int gc = (idx & 63) ^ (((row >> 1) & 3) << 4);
    gload16(Ag + (size_t)row * ldaB + gc, As + idx);
    gload16(Bg + (size_t)row * ldbB + gc, Bs + idx);
  }
}

// One BK=32 K-step; kb arrives pre-XORed with S(l&15).
__device__ __forceinline__ void comp32(const char* As, const char* Bs,
                                       f32x4 (&acc)[4][4],
                                       int arow, int brow, int kb) {
  bf16x8 af[4], bfr[4];
  #pragma unroll
  for (int i = 0; i < 4; ++i) {
    af[i]  = *(const bf16x8*)(As + (arow + i * 16) * 64 + kb);
    bfr[i] = *(const bf16x8*)(Bs + (brow + i * 16) * 64 + kb);
  }
  __builtin_amdgcn_s_setprio(1);
  #pragma unroll
  for (int mf = 0; mf < 4; ++mf)
    #pragma unroll
    for (int nf = 0; nf < 4; ++nf)
      acc[mf][nf] = __builtin_amdgcn_mfma_f32_16x16x32_bf16(
          af[mf], bfr[nf], acc[mf][nf], 0, 0, 0);
  __builtin_amdgcn_s_setprio(0);
}

// Depth-3 counted vmcnt; requires kIters >= 3 (all users >= 4).
__device__ __forceinline__ void gemm256c(const char* Ab, int ldaB,
                                         const char* Bb, int ldbB,
                                         int kIters, f32x4 (&acc)[4][4],
                                         char* lds) {
  const int t = (int)threadIdx.x, l = t & 63, w = t >> 6;
  const int arow = (w >> 1) * 64 + (l & 15);
  const int brow = (w & 1) * 64 + (l & 15);
  const int kb = ((l >> 4) * 16) ^ ((((l & 15) >> 1) & 3) << 4);
  char* A0 = lds;          char* B0 = lds + 8192;
  char* A1 = lds + 16384;  char* B1 = lds + 24576;
  char* A2 = lds + 32768;  char* B2 = lds + 40960;
  stage32(Ab,      ldaB, Bb,      ldbB, A0, B0, t);
  stage32(Ab + 64, ldaB, Bb + 64, ldbB, A1, B1, t);
  for (int kt = 0; kt < kIters - 2; ++kt) {
    stage32(Ab + (size_t)(kt + 2) * 64, ldaB,
            Bb + (size_t)(kt + 2) * 64, ldbB, A2, B2, t);
    vwait<8>();
    barrier_();
    comp32(A0, B0, acc, arow, brow, kb);
    barrier_();
    char* ta = A0; A0 = A1; A1 = A2; A2 = ta;
    char* tb = B0; B0 = B1; B1 = B2; B2 = tb;
  }
  vwait<4>();
  barrier_();
  comp32(A0, B0, acc, arow, brow, kb);
  vwait<0>();
  barrier_();
  comp32(A1, B1, acc, arow, brow, kb);
}

#define EPI_SETUP \
  const int el = (int)threadIdx.x & 63, ew = (int)threadIdx.x >> 6; \
  const int rb = (ew >> 1) * 64 + ((el >> 4) << 2); \
  const int cb = (ew & 1) * 64 + (el & 15);

// ---------------- weight convert ----------------
struct CvtW { const float* s[13]; };
__global__ __launch_bounds__(256) void k_cvtw(CvtW cw, u16* dst) {
  const int seg = blockIdx.y;
  const int i = (blockIdx.x * 256 + threadIdx.x) * 4;
  const int sz = (seg == 12) ? 786432 : 32768;
  if (i >= sz) return;
  size_t off = (seg < 9) ? (size_t)seg * 32768
             : (seg < 12) ? 294912 + (size_t)(seg - 9) * 32768
                          : 393216;
  f32x4 v = *(const f32x4*)(cw.s[seg] + i);
  u16x4 o; o.x = f2bf(v[0]); o.y = f2bf(v[1]); o.z = f2bf(v[2]); o.w = f2bf(v[3]);
  *(u16x4*)(dst + off + i) = o;
}

// ---------------- x transpose-convert: (b,c,n) -> xbT[vb][q][c] ----------------
__global__ __launch_bounds__(256) void k_cvtx(const float* x0, const float* x1,
                                              const float* x2, u16* XT) {
  __shared__ float tile[64][65];
  const int t = threadIdx.x;
  const int q0 = blockIdx.x * 64, c0 = blockIdx.y * 64;
  const int vb = blockIdx.z, v = vb >> 2, b = vb & 3;
  const float* src = (v == 0 ? x0 : v == 1 ? x1 : x2) + ((size_t)b * C_ + c0) * N_ + q0;
  #pragma unroll
  for (int i = 0; i < 4; ++i) {
    int idx = t + i * 256;
    int r = idx >> 4, q4 = (idx & 15) * 4;
    f32x4 val = *(const f32x4*)(src + (size_t)r * N_ + q4);
    tile[r][q4 + 0] = val[0]; tile[r][q4 + 1] = val[1];
    tile[r][q4 + 2] = val[2]; tile[r][q4 + 3] = val[3];
  }
  __syncthreads();
  u16* dst = XT + ((size_t)vb * N_ + q0) * 256 + c0;
  const int q = t >> 2, cp = (t & 3) * 16;
  u16 tmp[16];
  #pragma unroll
  for (int jj = 0; jj < 16; ++jj) tmp[jj] = f2bf(tile[cp + jj][q]);
  #pragma unroll
  for (int s4 = 0; s4 < 4; ++s4) {
    u16x4 o; o.x = tmp[s4 * 4]; o.y = tmp[s4 * 4 + 1];
    o.z = tmp[s4 * 4 + 2]; o.w = tmp[s4 * 4 + 3];
    *(u16x4*)(dst + (size_t)q * 256 + cp + s4 * 4) = o;
  }
}

// ---------------- proj (256t, grid (18,1,36), kIters=8) ----------------
struct ProjA { const float* bias[9]; };
__global__ __launch_bounds__(256) void k_proj(const u16* WB, const u16* XT,
                                              u16* TH, u16* PH, u16* GP, ProjA pa) {
  __shared__ char lds[49152];
  const int col0 = blockIdx.x * 128;                 // q
  const int p = blockIdx.z >> 2, b = blockIdx.z & 3;
  const int v = p / 3, pt = p % 3;
  const char* Ab = (const char*)(WB + (size_t)p * 32768);
  const char* Bb = (const char*)(XT + ((size_t)(v * 4 + b) * N_ + col0) * 256);
  f32x4 acc[4][4] = {};
  gemm256c(Ab, 512, Bb, 512, 8, acc, lds);
  EPI_SETUP;
  const float* bias = pa.bias[p];
  if (pt == 0) {                                     // g -> (ci, m) natural
    u16* dst = GP + (size_t)(v * 4 + b) * CI_ * N_;
    #pragma unroll
    for (int mf = 0; mf < 4; ++mf) {
      const int row = rb + mf * 16;
      f32x4 bv = *(const f32x4*)(bias + row);
      #pragma unroll
      for (int nf = 0; nf < 4; ++nf) {
        const int col = col0 + cb + nf * 16;
        #pragma unroll
        for (int r = 0; r < 4; ++r)
          dst[(size_t)(row + r) * N_ + col] = f2bf(acc[mf][nf][r] + bv[r]);
      }
    }
  } else {                                           // theta/phi -> (q, ci)
    u16* dst = (pt == 1 ? TH : PH) + (size_t)(v * 4 + b) * N_ * CI_;
    #pragma unroll
    for (int mf = 0; mf < 4; ++mf) {
      const int row = rb + mf * 16;                  // ci
      f32x4 bv = *(const f32x4*)(bias + row);
      #pragma unroll
      for (int nf = 0; nf < 4; ++nf) {
        const int col = col0 + cb + nf * 16;         // q
        u16x4 o;
        o.x = f2bf(acc[mf][nf][0] + bv[0]); o.y = f2bf(acc[mf][nf][1] + bv[1]);
        o.z = f2bf(acc[mf][nf][2] + bv[2]); o.w = f2bf(acc[mf][nf][3] + bv[3]);
        *(u16x4*)(dst + (size_t)col * CI_ + row) = o;
      }
    }
  }
}

// ---------------- score (256t, grid (18,18,3), kIters=4) ----------------
__global__ __launch_bounds__(256) void k_score(const u16* TH, const u16* PH,
                                               u16* F, int b) {
  __shared__ char lds[49152];
  const int col0 = blockIdx.x * 128;   // k
  const int row0 = blockIdx.y * 128;   // q
  const int br = blockIdx.z;
  const char* Ab = (const char*)(TH + ((size_t)(br * 4 + b) * N_ + row0) * CI_);
  const char* Bb = (const char*)(PH + ((size_t)(br * 4 + b) * N_ + col0) * CI_);
  f32x4 acc[4][4] = {};
  gemm256c(Ab, 256, Bb, 256, 4, acc, lds);
  EPI_SETUP;
  const int t = (int)threadIdx.x;
  __syncthreads();                      // K-loop LDS reads done; reuse as [128][136]
  u16* tl = (u16*)lds;
  #pragma unroll
  for (int mf = 0; mf < 4; ++mf)
    #pragma unroll
    for (int nf = 0; nf < 4; ++nf)
      #pragma unroll
      for (int r = 0; r < 4; ++r)
        tl[(rb + mf * 16 + r) * 136 + cb + nf * 16] = f2h(acc[mf][nf][r]);
  __syncthreads();
  u16* dst = F + (size_t)br * NN_;
  const int k8 = (t & 15) * 8;
  #pragma unroll
  for (int rr = 0; rr < 8; ++rr) {
    const int q = (t >> 4) + rr * 16;
    *(u16x8*)(dst + (size_t)(row0 + q) * N_ + col0 + k8) =
        *(const u16x8*)(tl + q * 136 + k8);
  }
}

// ---------------- softsum: A-row = sum of 3 softmaxes, fused 3-way reduce ----
__global__ __launch_bounds__(256) void k_softsum(const u16* F, u16* Abf, int b) {
  __shared__ float red[3][4];
  const int q = blockIdx.x, t = threadIdx.x;
  const bool ext = (t < 32);
  float e[3][16];
  float s0 = 0.f, s1 = 0.f, s2 = 0.f;
  #pragma unroll
  for (int i = 0; i < 3; ++i) {
    const u16* base = F + (size_t)i * NN_ + (size_t)q * N_;
    u16x8 a = *(const u16x8*)(base + t * 8);
    #pragma unroll
    for (int jj = 0; jj < 8; ++jj) e[i][jj] = __expf(h2f(a.e[jj]));
    if (ext) {
      u16x8 c = *(const u16x8*)(base + 2048 + t * 8);
      #pragma unroll
      for (int jj = 0; jj < 8; ++jj) e[i][8 + jj] = __expf(h2f(c.e[jj]));
    } else {
      #pragma unroll
      for (int jj = 0; jj < 8; ++jj) e[i][8 + jj] = 0.f;
    }
    float ss = 0.f;
    #pragma unroll
    for (int s = 0; s < 16; ++s) ss += e[i][s];
    if (i == 0) s0 = ss; else if (i == 1) s1 = ss; else s2 = ss;
  }
  #pragma unroll
  for (int o = 32; o; o >>= 1) {
    s0 += __shfl_xor(s0, o);
    s1 += __shfl_xor(s1, o);
    s2 += __shfl_xor(s2, o);
  }
  const int w = t >> 6;
  __syncthreads();
  if ((t & 63) == 0) { red[0][w] = s0; red[1][w] = s1; red[2][w] = s2; }
  __syncthreads();
  const float inv0 = 1.f / (red[0][0] + red[0][1] + red[0][2] + red[0][3]);
  const float inv1 = 1.f / (red[1][0] + red[1][1] + red[1][2] + red[1][3]);
  const float inv2 = 1.f / (red[2][0] + red[2][1] + red[2][2] + red[2][3]);
  u16* dst = Abf + ((size_t)b * N_ + q) * N_;
  u16x8 o;
  #pragma unroll
  for (int jj = 0; jj < 8; ++jj)
    o.e[jj] = f2bf(e[0][jj] * inv0 + e[1][jj] * inv1 + e[2][jj] * inv2);
  *(u16x8*)(dst + t * 8) = o;
  if (ext) {
    #pragma unroll
    for (int jj = 0; jj < 8; ++jj)
      o.e[jj] = f2bf(e[0][8 + jj] * inv0 + e[1][8 + jj] * inv1 + e[2][8 + jj] * inv2);
    *(u16x8*)(dst + 2048 + t * 8) = o;
  }
}

// ---------------- pv (256t, K-split x2, grid 432, kIters=36) ----------------
// Epilogue: bf16 partials via LDS u16 tile [128q][72], u16x4 stores along jc.
__global__ __launch_bounds__(256) void k_pv(const u16* Abf, const u16* GP,
                                            u16* P) {
  __shared__ char lds[49152];
  const int lid = xcd_swz();
  const int j = lid % 3;
  const int row0 = ((lid / 3) % 18) * 128; // q
  const int z = lid / 54;
  const int b = z >> 1, s = z & 1;
  const char* Ab = (const char*)(Abf + ((size_t)b * N_ + row0) * N_ + s * 1152);
  const char* Bb = (const char*)(GP + (size_t)(j * 4 + b) * CI_ * N_ + s * 1152);
  f32x4 acc[4][4] = {};
  gemm256c(Ab, 4608, Bb, 4608, 36, acc, lds);
  EPI_SETUP;
  const int t = (int)threadIdx.x;
  u16* dst = P + ((size_t)(s * 4 + b) * N_) * 384;
  u16* tl = (u16*)lds;
  const int jc4 = (t & 15) * 4;
  #pragma unroll
  for (int p = 0; p < 2; ++p) {
    __syncthreads();
    if ((ew & 1) == p) {
      #pragma unroll
      for (int mf = 0; mf < 4; ++mf)
        #pragma unroll
        for (int nf = 0; nf < 4; ++nf)
          #pragma unroll
          for (int r = 0; r < 4; ++r)
            tl[(rb + mf * 16 + r) * 72 + (el & 15) + nf * 16] =
                f2bf(acc[mf][nf][r]);
    }
    __syncthreads();
    #pragma unroll
    for (int rr = 0; rr < 8; ++rr) {
      const int q = (t >> 4) + rr * 16;
      *(u16x4*)(dst + (size_t)(row0 + q) * 384 + j * 128 + p * 64 + jc4) =
          *(const u16x4*)(tl + q * 72 + jc4);
    }
  }
}

__global__ __launch_bounds__(256) void k_pvred(const u16* P, u16* Y) {
  const size_t i8 = ((size_t)blockIdx.x * 256 + threadIdx.x) * 8;
  constexpr size_t HALF = (size_t)4 * N_ * 384;
  u16x8 a = *(const u16x8*)(P + i8);
  u16x8 c = *(const u16x8*)(P + HALF + i8);
  u16x8 o;
  #pragma unroll
  for (int jj = 0; jj < 8; ++jj)
    o.e[jj] = f2bf(bf2f(a.e[jj]) + bf2f(c.e[jj]));
  *(u16x8*)(Y + i8) = o;
}

// ---------------- zcat (256t, grid (18,2,12), kIters=4) ----------------
struct ZA { const float* x[3]; const float* wzb[3]; const float* dww; const float* dwb; };
__global__ __launch_bounds__(256) void k_zcat(const u16* WZ, const u16* Y,
                                              u16* DW, ZA za) {
  __shared__ char lds[49152];
  const int col0 = blockIdx.x * 128;                 // q
  const int row0 = blockIdx.y * 128;                 // c within 256
  const int j = blockIdx.z >> 2, b = blockIdx.z & 3;
  const char* Ab = (const char*)(WZ + (size_t)j * 32768 + (size_t)row0 * CI_);
  const char* Bb = (const char*)(Y + ((size_t)b * N_ + col0) * 384 + j * CI_);
  f32x4 acc[4][4] = {};
  gemm256c(Ab, 256, Bb, 768, 4, acc, lds);
  EPI_SETUP;
  const float* xj = za.x[j];
  #pragma unroll
  for (int mf = 0; mf < 4; ++mf) {
    const int cl = row0 + rb + mf * 16;              // 0..255
    const int cg = j * 256 + cl;
    f32x4 wb = *(const f32x4*)(za.wzb[j] + cl);
    f32x4 sc = *(const f32x4*)(za.dww + cg);
    f32x4 sb = *(const f32x4*)(za.dwb + cg);
    #pragma unroll
    for (int nf = 0; nf < 4; ++nf) {
      const int qg = col0 + cb + nf * 16;
      u16x4 o;
      o.x = f2bf((acc[mf][nf][0] + wb[0] + xj[((size_t)b * C_ + cl + 0) * N_ + qg]) * sc[0] + sb[0]);
      o.y = f2bf((acc[mf][nf][1] + wb[1] + xj[((size_t)b * C_ + cl + 1) * N_ + qg]) * sc[1] + sb[1]);
      o.z = f2bf((acc[mf][nf][2] + wb[2] + xj[((size_t)b * C_ + cl + 2) * N_ + qg]) * sc[2] + sb[2]);
      o.w = f2bf((acc[mf][nf][3] + wb[3] + xj[((size_t)b * C_ + cl + 3) * N_ + qg]) * sc[3] + sb[3]);
      *(u16x4*)(DW + ((size_t)b * N_ + qg) * 768 + cg) = o;
    }
  }
}

// ---------------- final (256t, grid 576 swizzled, kIters=24) -----------------
__global__ __launch_bounds__(256) void k_final(const u16* PWb, const u16* DW,
                                               const float* pwb, const float* xin,
                                               const float* pp, float* out) {
  __shared__ char lds[49152];
  const int lid = xcd_swz();
  const int row0 = (lid % 18) * 128;        // q strip
  const int col0 = ((lid / 18) % 8) * 128;  // o strip
  const int b = lid / 144;
  const char* Ab = (const char*)(DW + ((size_t)b * N_ + row0) * 768);
  const char* Bb = (const char*)(PWb + (size_t)col0 * 768);
  EPI_SETUP;
  const int t = (int)threadIdx.x;
  const float pscale = pp[0];
  const int q4 = (t & 31) * 4;
  const int ob = (t >> 5) * 8;
  f32x4 xv[2][8];
  #pragma unroll
  for (int p = 0; p < 2; ++p)
    #pragma unroll
    for (int rr = 0; rr < 8; ++rr)
      xv[p][rr] = *(const f32x4*)(
          xin + ((size_t)b * 1024 + col0 + p * 64 + ob + rr) * N_ + row0 + q4);
  f32x4 acc[4][4] = {};
  gemm256c(Ab, 1536, Bb, 1536, 24, acc, lds);
  float* tl = (float*)lds;
  #pragma unroll
  for (int p = 0; p < 2; ++p) {
    __syncthreads();
    if ((ew & 1) == p) {                   // this wave-column owns o-half p
      #pragma unroll
      for (int mf = 0; mf < 4; ++mf)
        #pragma unroll
        for (int nf = 0; nf < 4; ++nf)
          #pragma unroll
          for (int r = 0; r < 4; ++r)
            tl[((el & 15) + nf * 16) * 132 + rb + mf * 16 + r] = acc[mf][nf][r];
    }
    __syncthreads();
    #pragma unroll
    for (int rr = 0; rr < 8; ++rr) {
      const int og = col0 + p * 64 + ob + rr;
      const float bb = pwb[og];
      f32x4 a4 = *(const f32x4*)(tl + (ob + rr) * 132 + q4);
      f32x4 o4;
      #pragma unroll
      for (int r = 0; r < 4; ++r)
        o4[r] = xv[p][rr][r] + pscale * (a4[r] + bb);
      *(f32x4*)(out + ((size_t)b * 1024 + og) * N_ + row0 + q4) = o4;
    }
  }
}

// ---------------------------------------------------------------------------
extern "C" void kernel_launch(void* const* d_in, const int* in_sizes, int n_in,
                              void* d_out, int out_size, void* d_ws, size_t ws_size,
                              hipStream_t stream) {
  const float* x0  = (const float*)d_in[0];
  const float* x1  = (const float*)d_in[1];
  const float* x2  = (const float*)d_in[2];
  const float* xin = (const float*)d_in[3];
  const float* g_w = (const float*)d_in[4];
  const float* g_b = (const float*)d_in[5];
  const float* thw[3] = {(const float*)d_in[6],  (const float*)d_in[10], (const float*)d_in[14]};
  const float* thb[3] = {(const float*)d_in[7],  (const float*)d_in[11], (const float*)d_in[15]};
  const float* phw[3] = {(const float*)d_in[8],  (const float*)d_in[12], (const float*)d_in[16]};
  const float* phb[3] = {(const float*)d_in[9],  (const float*)d_in[13], (const float*)d_in[17]};
  const float* Wm[3]  = {(const float*)d_in[18], (const float*)d_in[20], (const float*)d_in[22]};
  const float* Wmb[3] = {(const float*)d_in[19], (const float*)d_in[21], (const float*)d_in[23]};
  const float* dww = (const float*)d_in[24];
  const float* dwb = (const float*)d_in[25];
  const float* pww = (const float*)d_in[26];
  const float* pwb = (const float*)d_in[27];
  const float* pp  = (const float*)d_in[28];

  char* wsb = (char*)d_ws;
  u16*   WB  = (u16*)(wsb + B_WB);
  u16*   WZ  = (u16*)(wsb + B_WZ);
  u16*   PW  = (u16*)(wsb + B_PW);
  u16*   XT  = (u16*)(wsb + B_R1);
  u16*   Y   = (u16*)(wsb + B_R1);   // overlays XT (dead after k_proj)
  u16*   TH  = (u16*)(wsb + B_R2);
  u16*   PH  = TH + (size_t)3 * B_ * N_ * CI_;
  u16*   DW  = (u16*)(wsb + B_R2);   // overlays TH/PH (dead after last k_score)
  u16*   GP  = (u16*)(wsb + B_GP);
  u16*   Fh  = (u16*)(wsb + B_F);    // fp16 scores, per batch
  u16*   Pp  = (u16*)(wsb + B_F);    // bf16 pv partials overlay (Fh dead)
  u16*   Abf = (u16*)(wsb + B_A);

  CvtW cw;
  cw.s[0] = g_w; cw.s[1] = thw[0]; cw.s[2] = phw[0];
  cw.s[3] = g_w; cw.s[4] = thw[1]; cw.s[5] = phw[1];
  cw.s[6] = g_w; cw.s[7] = thw[2]; cw.s[8] = phw[2];
  cw.s[9] = Wm[0]; cw.s[10] = Wm[1]; cw.s[11] = Wm[2];
  cw.s[12] = pww;

  ProjA pa;
  pa.bias[0] = g_b; pa.bias[1] = thb[0]; pa.bias[2] = phb[0];
  pa.bias[3] = g_b; pa.bias[4] = thb[1]; pa.bias[5] = phb[1];
  pa.bias[6] = g_b; pa.bias[7] = thb[2]; pa.bias[8] = phb[2];

  ZA za;
  za.x[0] = x0; za.x[1] = x1; za.x[2] = x2;
  za.wzb[0] = Wmb[0]; za.wzb[1] = Wmb[1]; za.wzb[2] = Wmb[2];
  za.dww = dww; za.dwb = dwb;

  k_cvtw<<<dim3(768, 13), 256, 0, stream>>>(cw, WB);
  k_cvtx<<<dim3(36, 4, 12), 256, 0, stream>>>(x0, x1, x2, XT);
  k_proj<<<dim3(18, 1, 36), 256, 0, stream>>>(WB, XT, TH, PH, GP, pa);
  for (int b = 0; b < B_; ++b) {
    k_score  <<<dim3(18, 18, 3), 256, 0, stream>>>(TH, PH, Fh, b);
    k_softsum<<<dim3(N_),        256, 0, stream>>>(Fh, Abf, b);
  }
  k_pv   <<<dim3(432),  256, 0, stream>>>(Abf, GP, Pp);
  k_pvred<<<dim3(1728), 256, 0, stream>>>(Pp, Y);
  k_zcat <<<dim3(18, 2, 12), 256, 0, stream>>>(WZ, Y, DW, za);
  k_final<<<dim3(576),  256, 0, stream>>>(PW, DW, pwb, xin, pp, (float*)d_out);
}